// Round 2
// baseline (21545.129 us; speedup 1.0000x reference)
//
#include <hip/hip_runtime.h>
#include <math.h>

#define N_SIMP 400000
#define E_NNZ  2400000
#define FIN    32
#define HDIM   64
#define KAPPA  3
#define G_NUM  512
#define NOUT   8
#define BN_EPS 1e-5

__device__ __forceinline__ float elu_f(float x) {
    return x > 0.f ? x : expm1f(x);
}

// out[h] = bh[h] + sum_k bl[k][h] + bu[k][h]
__global__ void combine_bias_kernel(const float* __restrict__ bh,
                                    const float* __restrict__ bl,
                                    const float* __restrict__ bu,
                                    float* __restrict__ out) {
    int h = threadIdx.x;
    float acc = bh[h];
    for (int k = 0; k < KAPPA; ++k) acc += bl[k * HDIM + h] + bu[k * HDIM + h];
    out[h] = acc;
}

// y[row, 4g:4g+4] += val * x[col, 4g:4g+4]; runtime channel-block width (CB = 4<<lg_groups... CB/4 groups)
__global__ void spmm_atomic_kernel(const int* __restrict__ ei,
                                   const float* __restrict__ vals,
                                   const float* __restrict__ xin, int src_stride,
                                   float* __restrict__ yout, int dst_stride,
                                   int lg_groups, int total) {
    int tid = blockIdx.x * 256 + threadIdx.x;
    if (tid >= total) return;
    int e = tid >> lg_groups;
    int g = tid & ((1 << lg_groups) - 1);
    int row = ei[e];
    int col = ei[E_NNZ + e];
    float v = vals[e];
    const float4 xv = *(const float4*)(xin + (size_t)col * src_stride + g * 4);
    float* yp = yout + (size_t)row * dst_stride + g * 4;
    atomicAdd(yp + 0, v * xv.x);
    atomicAdd(yp + 1, v * xv.y);
    atomicAdd(yp + 2, v * xv.z);
    atomicAdd(yp + 3, v * xv.w);
}

// z[row,h] (=|+=) in[row,0:K] @ W[0:K,h] (+ bias on init). Block = 4 rows x 64 cols.
// in is N x K contiguous; W is K x 64 contiguous.
__global__ void matmul_acc_kernel(const float* __restrict__ in, int K,
                                  const float* __restrict__ W,
                                  const float* __restrict__ bias,
                                  float* __restrict__ z, int init) {
    __shared__ float Ws[64 * 64];
    __shared__ float ins[4 * 64];
    int tid = threadIdx.x;
    for (int idx = tid; idx < K * HDIM; idx += 256) Ws[idx] = W[idx];
    int block_row = blockIdx.x * 4;
    for (int idx = tid; idx < 4 * K; idx += 256) {
        int r = idx / K, k = idx - r * K;
        int row = block_row + r;
        ins[r * 64 + k] = (row < N_SIMP) ? in[(size_t)row * K + k] : 0.f;
    }
    __syncthreads();
    int h = tid & 63;
    int r = tid >> 6;
    int row = block_row + r;
    if (row >= N_SIMP) return;
    float acc = init ? bias[h] : z[(size_t)row * HDIM + h];
    for (int k = 0; k < K; ++k) acc += ins[r * 64 + k] * Ws[k * HDIM + h];
    z[(size_t)row * HDIM + h] = acc;
}

// per-column sum & sumsq over N rows (double atomics into stats[0:64], stats[64:128])
__global__ void bn_stats_kernel(const float* __restrict__ z, double* __restrict__ stats) {
    __shared__ double s1[256], s2[256];
    int tid = threadIdx.x;
    const long long total = (long long)N_SIMP * HDIM;
    double sum = 0.0, sq = 0.0;
    for (long long idx = (long long)blockIdx.x * 256 + tid; idx < total;
         idx += (long long)gridDim.x * 256) {
        float v = z[idx];
        sum += v;
        sq += (double)v * v;
    }
    s1[tid] = sum; s2[tid] = sq;
    __syncthreads();
    if (tid < 64) {
        double a = s1[tid] + s1[tid + 64] + s1[tid + 128] + s1[tid + 192];
        double b = s2[tid] + s2[tid + 64] + s2[tid + 128] + s2[tid + 192];
        atomicAdd(&stats[tid], a);
        atomicAdd(&stats[64 + tid], b);
    }
}

// in-place: z = elu((z - mean) * gamma / sqrt(var+eps) + beta)
__global__ void bn_elu_kernel(float* __restrict__ z, const double* __restrict__ stats,
                              const float* __restrict__ gamma, const float* __restrict__ beta) {
    __shared__ float scale_s[64], shift_s[64];
    int tid = threadIdx.x;
    if (tid < 64) {
        double mean = stats[tid] / (double)N_SIMP;
        double var = stats[64 + tid] / (double)N_SIMP - mean * mean;
        double sc = (double)gamma[tid] / sqrt(var + BN_EPS);
        scale_s[tid] = (float)sc;
        shift_s[tid] = (float)((double)beta[tid] - mean * sc);
    }
    __syncthreads();
    const long long total = (long long)N_SIMP * HDIM;
    for (long long idx = (long long)blockIdx.x * 256 + tid; idx < total;
         idx += (long long)gridDim.x * 256) {
        int h = (int)(idx & 63);
        float v = z[idx] * scale_s[h] + shift_s[h];
        z[idx] = elu_f(v);
    }
}

// per-graph max & mean pool over sorted batch_index, then elu; gbuf[g] = [elu(max)|elu(mean)]
__global__ void pool_kernel(const float* __restrict__ hbuf, const int* __restrict__ bidx,
                            float* __restrict__ gbuf) {
    __shared__ float smax[256], ssum[256];
    int g = blockIdx.x;
    int tid = threadIdx.x;
    int lo = 0, hi = N_SIMP;
    while (lo < hi) { int mid = (lo + hi) >> 1; if (bidx[mid] < g) lo = mid + 1; else hi = mid; }
    int start = lo;
    hi = N_SIMP;
    while (lo < hi) { int mid = (lo + hi) >> 1; if (bidx[mid] < g + 1) lo = mid + 1; else hi = mid; }
    int end = lo;
    int h = tid & 63, rep = tid >> 6;
    float mx = -INFINITY, sm = 0.f;
    for (int i = start + rep; i < end; i += 4) {
        float v = hbuf[(size_t)i * HDIM + h];
        mx = fmaxf(mx, v);
        sm += v;
    }
    smax[tid] = mx; ssum[tid] = sm;
    __syncthreads();
    if (tid < 64) {
        float m = fmaxf(fmaxf(smax[tid], smax[tid + 64]), fmaxf(smax[tid + 128], smax[tid + 192]));
        float s = ssum[tid] + ssum[tid + 64] + ssum[tid + 128] + ssum[tid + 192];
        int cnt = end - start;
        float mean = s / fmaxf((float)cnt, 1.f);
        gbuf[g * 128 + tid] = elu_f(m);
        gbuf[g * 128 + 64 + tid] = elu_f(mean);
    }
}

// out[g] = relu(g_row @ W1 + b1) @ W2 + b2 ; one block (64 thr) per graph
__global__ void mlp_kernel(const float* __restrict__ gbuf, const float* __restrict__ W1,
                           const float* __restrict__ b1, const float* __restrict__ W2,
                           const float* __restrict__ b2, float* __restrict__ out) {
    __shared__ float gs[128];
    __shared__ float hs[64];
    int g = blockIdx.x, tid = threadIdx.x;
    gs[tid] = gbuf[g * 128 + tid];
    gs[64 + tid] = gbuf[g * 128 + 64 + tid];
    __syncthreads();
    float acc = b1[tid];
#pragma unroll
    for (int k = 0; k < 128; ++k) acc += gs[k] * W1[k * 64 + tid];
    hs[tid] = fmaxf(acc, 0.f);
    __syncthreads();
    if (tid < 8) {
        float o = b2[tid];
#pragma unroll
        for (int k = 0; k < 64; ++k) o += hs[k] * W2[k * 8 + tid];
        out[g * 8 + tid] = o;
    }
}

// ---- host-side helpers ----
static inline void run_chain(const float* seed, int seed_stride, int Fin,
                             const int* ei, const float* vals,
                             const float* Wchain,  // (KAPPA, Fin, 64)
                             float* z, float* fA, float* fB, int CB,
                             hipStream_t stream) {
    int lg = (CB == 64) ? 4 : (CB == 32) ? 3 : (CB == 16) ? 2 : 1;
    int nblk = Fin / CB;
    const int MM_BLOCKS = N_SIMP / 4;
    int total = E_NNZ << lg;
    int sblocks = (total + 255) / 256;
    size_t bufbytes = (size_t)N_SIMP * CB * 4;
    for (int p = 0; p < nblk; ++p) {
        const float* cur = seed + p * CB;
        int cur_stride = seed_stride;
        float* bufs[2] = {fA, fB};
        int pp = 0;
        for (int k = 0; k < KAPPA; ++k) {
            float* nxt = bufs[pp]; pp ^= 1;
            hipMemsetAsync(nxt, 0, bufbytes, stream);
            spmm_atomic_kernel<<<sblocks, 256, 0, stream>>>(ei, vals, cur, cur_stride,
                                                            nxt, CB, lg, total);
            matmul_acc_kernel<<<MM_BLOCKS, 256, 0, stream>>>(
                nxt, CB, Wchain + (size_t)k * Fin * HDIM + (size_t)p * CB * HDIM,
                nullptr, z, 0);
            cur = nxt;
            cur_stride = CB;
        }
    }
}

extern "C" void kernel_launch(void* const* d_in, const int* in_sizes, int n_in,
                              void* d_out, int out_size, void* d_ws, size_t ws_size,
                              hipStream_t stream) {
    const float* x     = (const float*)d_in[0];
    const int*   li    = (const int*)d_in[1];
    const float* lv    = (const float*)d_in[2];
    const int*   ui    = (const int*)d_in[3];
    const float* uv    = (const float*)d_in[4];
    const int*   bidx  = (const int*)d_in[5];
    const float* l0_Wl = (const float*)d_in[6];
    const float* l0_bl = (const float*)d_in[7];
    const float* l0_Wu = (const float*)d_in[8];
    const float* l0_bu = (const float*)d_in[9];
    const float* l0_Wh = (const float*)d_in[10];
    const float* l0_bh = (const float*)d_in[11];
    const float* l1_Wl = (const float*)d_in[12];
    const float* l1_bl = (const float*)d_in[13];
    const float* l1_Wu = (const float*)d_in[14];
    const float* l1_bu = (const float*)d_in[15];
    const float* l1_Wh = (const float*)d_in[16];
    const float* l1_bh = (const float*)d_in[17];
    const float* bn0_g = (const float*)d_in[18];
    const float* bn0_b = (const float*)d_in[19];
    const float* bn1_g = (const float*)d_in[20];
    const float* bn1_b = (const float*)d_in[21];
    const float* mW1   = (const float*)d_in[22];
    const float* mb1   = (const float*)d_in[23];
    const float* mW2   = (const float*)d_in[24];
    const float* mb2   = (const float*)d_in[25];
    float* out = (float*)d_out;

    // ---- workspace layout (bytes) ----
    char* base = (char*)d_ws;
    double* stats = (double*)base;            // 128 doubles = 1024 B
    float* cbias  = (float*)(base + 1024);    // 64 floats
    float* gbuf   = (float*)(base + 2048);    // 512*128 floats = 262144 B
    const size_t HOFF = 327680;               // h buffers start here (16B aligned)
    float* h0 = (float*)(base + HOFF);
    float* h1 = h0 + (size_t)N_SIMP * HDIM;
    float* fA = h1 + (size_t)N_SIMP * HDIM;
    const size_t fixed = HOFF + 2ull * N_SIMP * HDIM * 4;

    // pick channel-block width for chain buffers based on available workspace
    int CB1 = 8;
    for (int cb = 64; cb >= 8; cb >>= 1) {
        size_t need = fixed + 2ull * N_SIMP * cb * 4;
        if (need <= ws_size) { CB1 = cb; break; }
    }
    int CB0 = CB1 > FIN ? FIN : CB1;
    float* fB = fA + (size_t)N_SIMP * CB1;

    const int MM_BLOCKS = N_SIMP / 4;

    // ---------------- layer 0 (F_IN=32 -> H=64) ----------------
    combine_bias_kernel<<<1, 64, 0, stream>>>(l0_bh, l0_bl, l0_bu, cbias);
    matmul_acc_kernel<<<MM_BLOCKS, 256, 0, stream>>>(x, FIN, l0_Wh, cbias, h0, 1);
    run_chain(x, FIN, FIN, li, lv, l0_Wl, h0, fA, fB, CB0, stream);
    run_chain(x, FIN, FIN, ui, uv, l0_Wu, h0, fA, fB, CB0, stream);

    hipMemsetAsync(stats, 0, 128 * sizeof(double), stream);
    bn_stats_kernel<<<1024, 256, 0, stream>>>(h0, stats);
    bn_elu_kernel<<<2048, 256, 0, stream>>>(h0, stats, bn0_g, bn0_b);

    // ---------------- layer 1 (H=64 -> H=64) ----------------
    combine_bias_kernel<<<1, 64, 0, stream>>>(l1_bh, l1_bl, l1_bu, cbias);
    matmul_acc_kernel<<<MM_BLOCKS, 256, 0, stream>>>(h0, HDIM, l1_Wh, cbias, h1, 1);
    run_chain(h0, HDIM, HDIM, li, lv, l1_Wl, h1, fA, fB, CB1, stream);
    run_chain(h0, HDIM, HDIM, ui, uv, l1_Wu, h1, fA, fB, CB1, stream);

    hipMemsetAsync(stats, 0, 128 * sizeof(double), stream);
    bn_stats_kernel<<<1024, 256, 0, stream>>>(h1, stats);
    bn_elu_kernel<<<2048, 256, 0, stream>>>(h1, stats, bn1_g, bn1_b);

    // ---------------- pool + MLP ----------------
    pool_kernel<<<G_NUM, 256, 0, stream>>>(h1, bidx, gbuf);
    mlp_kernel<<<G_NUM, 64, 0, stream>>>(gbuf, mW1, mb1, mW2, mb2, out);
}

// Round 5
// 5752.924 us; speedup vs baseline: 3.7451x; 3.7451x over previous
//
#include <hip/hip_runtime.h>
#include <hip/hip_bf16.h>
#include <math.h>

#define N_SIMP 400000
#define E_NNZ  2400000
#define FIN    32
#define HDIM   64
#define KAPPA  3
#define G_NUM  512
#define NOUT   8
#define BN_EPS 1e-5
#define CB     32   // chain block width (bf16)

typedef __hip_bfloat16 bf16;

__device__ __forceinline__ float elu_f(float x) {
    return x > 0.f ? x : expm1f(x);
}

// ---------------- CSR build (rp doubles as fill; no rp[N] needed) ----------------

__global__ void hist_kernel(const int* __restrict__ ei, int* __restrict__ rp) {
    int e = blockIdx.x * 256 + threadIdx.x;
    if (e >= E_NNZ) return;
    atomicAdd(&rp[ei[e]], 1);
}

// per-1024-block exclusive scan (in place) + block sums
__global__ void scan_block_kernel(int* __restrict__ data, int* __restrict__ bsum, int n) {
    __shared__ int sdata[256];
    int t = threadIdx.x;
    int base = blockIdx.x * 1024 + t * 4;
    int v0 = (base + 0 < n) ? data[base + 0] : 0;
    int v1 = (base + 1 < n) ? data[base + 1] : 0;
    int v2 = (base + 2 < n) ? data[base + 2] : 0;
    int v3 = (base + 3 < n) ? data[base + 3] : 0;
    int tsum = v0 + v1 + v2 + v3;
    sdata[t] = tsum;
    __syncthreads();
    for (int off = 1; off < 256; off <<= 1) {
        int val = (t >= off) ? sdata[t - off] : 0;
        __syncthreads();
        sdata[t] += val;
        __syncthreads();
    }
    if (t == 255) bsum[blockIdx.x] = sdata[255];
    int run = sdata[t] - tsum;
    if (base + 0 < n) { data[base + 0] = run; } run += v0;
    if (base + 1 < n) { data[base + 1] = run; } run += v1;
    if (base + 2 < n) { data[base + 2] = run; } run += v2;
    if (base + 3 < n) { data[base + 3] = run; }
}

__global__ void scan_top_kernel(int* __restrict__ bsum, int nb) {
    if (threadIdx.x == 0 && blockIdx.x == 0) {
        int run = 0;
        for (int i = 0; i < nb; ++i) { int t = bsum[i]; bsum[i] = run; run += t; }
    }
}

__global__ void add_off_kernel(int* __restrict__ rp, const int* __restrict__ bsum) {
    int i = blockIdx.x * 256 + threadIdx.x;
    if (i >= N_SIMP) return;
    rp[i] += bsum[i >> 10];
}

// scatter; rp[r] advances from exclusive-start to end offset
__global__ void scatter_kernel(const int* __restrict__ ei, const float* __restrict__ vals,
                               int* __restrict__ rp, int2* __restrict__ edge) {
    int e = blockIdx.x * 256 + threadIdx.x;
    if (e >= E_NNZ) return;
    int r = ei[e];
    int pos = atomicAdd(&rp[r], 1);
    edge[pos] = make_int2(ei[E_NNZ + e], __float_as_int(vals[e]));
}

// ---------------- compute kernels ----------------

__global__ void combine_bias_kernel(const float* __restrict__ bh,
                                    const float* __restrict__ bl,
                                    const float* __restrict__ bu,
                                    float* __restrict__ out) {
    int h = threadIdx.x;
    float acc = bh[h];
    for (int k = 0; k < KAPPA; ++k) acc += bl[k * HDIM + h] + bu[k * HDIM + h];
    out[h] = acc;
}

// CSR gather SpMM, 32 channels, bf16 out. 2 rows/wave, 8 rows/block.
// start = rp[row-1] (0 for row 0), end = rp[row]  (rp holds end offsets post-scatter)
template <typename SRC>
__global__ void spmm_csr_kernel(const int* __restrict__ rp, const int2* __restrict__ edge,
                                const SRC* __restrict__ src, int src_stride,
                                bf16* __restrict__ dst) {
    int tid = threadIdx.x;
    int lane = tid & 63;
    int wv = tid >> 6;
    int sub = lane >> 5;
    int h = lane & 31;
    int row = blockIdx.x * 8 + wv * 2 + sub;
    if (row >= N_SIMP) return;
    int s = (row == 0) ? 0 : rp[row - 1];
    int e = rp[row];
    float acc = 0.f;
    int j = s;
    for (; j + 1 < e; j += 2) {
        int2 e0 = edge[j];
        int2 e1 = edge[j + 1];
        float x0 = (float)src[(size_t)e0.x * src_stride + h];
        float x1 = (float)src[(size_t)e1.x * src_stride + h];
        acc += __int_as_float(e0.y) * x0;
        acc += __int_as_float(e1.y) * x1;
    }
    if (j < e) {
        int2 e0 = edge[j];
        acc += __int_as_float(e0.y) * (float)src[(size_t)e0.x * src_stride + h];
    }
    dst[(size_t)row * CB + h] = (bf16)acc;
}

// fused: z[row,h] += sum_{t=0..2} c_t[row,0:32] @ W[t][pcol:pcol+32, h]
// W layout (KAPPA, Fin, 64). Block = 4 rows x 64 cols.
__global__ void matmul3_acc_kernel(const bf16* __restrict__ c1, const bf16* __restrict__ c2,
                                   const bf16* __restrict__ c3,
                                   const float* __restrict__ W, int Fin, int pcol,
                                   float* __restrict__ z) {
    __shared__ float Ws[3][CB * 64];
    __shared__ float ins[3][4 * CB];
    int tid = threadIdx.x;
    for (int idx = tid; idx < 3 * CB * 64; idx += 256) {
        int t = idx / (CB * 64), rem = idx - t * (CB * 64);
        Ws[t][rem] = W[(size_t)t * Fin * 64 + (size_t)pcol * 64 + rem];
    }
    int block_row = blockIdx.x * 4;
    const bf16* cs[3] = {c1, c2, c3};
    for (int idx = tid; idx < 3 * 4 * CB; idx += 256) {
        int t = idx / (4 * CB), rem = idx - t * (4 * CB);
        int r = rem / CB, k = rem - r * CB;
        int row = block_row + r;
        ins[t][rem] = (row < N_SIMP) ? (float)cs[t][(size_t)row * CB + k] : 0.f;
    }
    __syncthreads();
    int h = tid & 63;
    int r = tid >> 6;
    int row = block_row + r;
    if (row >= N_SIMP) return;
    float acc = z[(size_t)row * 64 + h];
#pragma unroll
    for (int t = 0; t < 3; ++t)
#pragma unroll
        for (int k = 0; k < CB; ++k) acc += ins[t][r * CB + k] * Ws[t][k * 64 + h];
    z[(size_t)row * 64 + h] = acc;
}

// z[row,h] = bias[h] + in[row,0:K] @ W[0:K,h]
template <typename SRC>
__global__ void matmul_init_kernel(const SRC* __restrict__ in, int K,
                                   const float* __restrict__ W,
                                   const float* __restrict__ bias,
                                   float* __restrict__ z) {
    __shared__ float Ws[64 * 64];
    __shared__ float ins[4 * 64];
    int tid = threadIdx.x;
    for (int idx = tid; idx < K * 64; idx += 256) Ws[idx] = W[idx];
    int block_row = blockIdx.x * 4;
    for (int idx = tid; idx < 4 * K; idx += 256) {
        int r = idx / K, k = idx - r * K;
        int row = block_row + r;
        ins[r * K + k] = (row < N_SIMP) ? (float)in[(size_t)row * K + k] : 0.f;
    }
    __syncthreads();
    int h = tid & 63;
    int r = tid >> 6;
    int row = block_row + r;
    if (row >= N_SIMP) return;
    float acc = bias[h];
    for (int k = 0; k < K; ++k) acc += ins[r * K + k] * Ws[k * 64 + h];
    z[(size_t)row * 64 + h] = acc;
}

__global__ void bn_stats_kernel(const float* __restrict__ z, double* __restrict__ stats) {
    __shared__ double s1[256], s2[256];
    int tid = threadIdx.x;
    const long long total = (long long)N_SIMP * HDIM;
    double sum = 0.0, sq = 0.0;
    for (long long idx = (long long)blockIdx.x * 256 + tid; idx < total;
         idx += (long long)gridDim.x * 256) {
        float v = z[idx];
        sum += v;
        sq += (double)v * v;
    }
    s1[tid] = sum; s2[tid] = sq;
    __syncthreads();
    if (tid < 64) {
        double a = s1[tid] + s1[tid + 64] + s1[tid + 128] + s1[tid + 192];
        double b = s2[tid] + s2[tid + 64] + s2[tid + 128] + s2[tid + 192];
        atomicAdd(&stats[tid], a);
        atomicAdd(&stats[64 + tid], b);
    }
}

// layer-0 variant: h0bf = bf16(elu(bn(z)))
__global__ void bn_elu_bf16_kernel(const float* __restrict__ z, const double* __restrict__ stats,
                                   const float* __restrict__ gamma, const float* __restrict__ beta,
                                   bf16* __restrict__ out) {
    __shared__ float scale_s[64], shift_s[64];
    int tid = threadIdx.x;
    if (tid < 64) {
        double mean = stats[tid] / (double)N_SIMP;
        double var = stats[64 + tid] / (double)N_SIMP - mean * mean;
        double sc = (double)gamma[tid] / sqrt(var + BN_EPS);
        scale_s[tid] = (float)sc;
        shift_s[tid] = (float)((double)beta[tid] - mean * sc);
    }
    __syncthreads();
    const long long total = (long long)N_SIMP * HDIM;
    for (long long idx = (long long)blockIdx.x * 256 + tid; idx < total;
         idx += (long long)gridDim.x * 256) {
        int h = (int)(idx & 63);
        out[idx] = (bf16)elu_f(z[idx] * scale_s[h] + shift_s[h]);
    }
}

// layer-1 variant: z = elu(bn(z)) in place
__global__ void bn_elu_f32_kernel(float* __restrict__ z, const double* __restrict__ stats,
                                  const float* __restrict__ gamma, const float* __restrict__ beta) {
    __shared__ float scale_s[64], shift_s[64];
    int tid = threadIdx.x;
    if (tid < 64) {
        double mean = stats[tid] / (double)N_SIMP;
        double var = stats[64 + tid] / (double)N_SIMP - mean * mean;
        double sc = (double)gamma[tid] / sqrt(var + BN_EPS);
        scale_s[tid] = (float)sc;
        shift_s[tid] = (float)((double)beta[tid] - mean * sc);
    }
    __syncthreads();
    const long long total = (long long)N_SIMP * HDIM;
    for (long long idx = (long long)blockIdx.x * 256 + tid; idx < total;
         idx += (long long)gridDim.x * 256) {
        int h = (int)(idx & 63);
        z[idx] = elu_f(z[idx] * scale_s[h] + shift_s[h]);
    }
}

__global__ void pool_kernel(const float* __restrict__ hbuf, const int* __restrict__ bidx,
                            float* __restrict__ gbuf) {
    __shared__ float smax[256], ssum[256];
    int g = blockIdx.x;
    int tid = threadIdx.x;
    int lo = 0, hi = N_SIMP;
    while (lo < hi) { int mid = (lo + hi) >> 1; if (bidx[mid] < g) lo = mid + 1; else hi = mid; }
    int start = lo;
    hi = N_SIMP;
    while (lo < hi) { int mid = (lo + hi) >> 1; if (bidx[mid] < g + 1) lo = mid + 1; else hi = mid; }
    int end = lo;
    int h = tid & 63, rep = tid >> 6;
    float mx = -INFINITY, sm = 0.f;
    for (int i = start + rep; i < end; i += 4) {
        float v = hbuf[(size_t)i * HDIM + h];
        mx = fmaxf(mx, v);
        sm += v;
    }
    smax[tid] = mx; ssum[tid] = sm;
    __syncthreads();
    if (tid < 64) {
        float m = fmaxf(fmaxf(smax[tid], smax[tid + 64]), fmaxf(smax[tid + 128], smax[tid + 192]));
        float s = ssum[tid] + ssum[tid + 64] + ssum[tid + 128] + ssum[tid + 192];
        int cnt = end - start;
        float mean = s / fmaxf((float)cnt, 1.f);
        gbuf[g * 128 + tid] = elu_f(m);
        gbuf[g * 128 + 64 + tid] = elu_f(mean);
    }
}

__global__ void mlp_kernel(const float* __restrict__ gbuf, const float* __restrict__ W1,
                           const float* __restrict__ b1, const float* __restrict__ W2,
                           const float* __restrict__ b2, float* __restrict__ out) {
    __shared__ float gs[128];
    __shared__ float hs[64];
    int g = blockIdx.x, tid = threadIdx.x;
    gs[tid] = gbuf[g * 128 + tid];
    gs[64 + tid] = gbuf[g * 128 + 64 + tid];
    __syncthreads();
    float acc = b1[tid];
#pragma unroll
    for (int k = 0; k < 128; ++k) acc += gs[k] * W1[k * 64 + tid];
    hs[tid] = fmaxf(acc, 0.f);
    __syncthreads();
    if (tid < 8) {
        float o = b2[tid];
#pragma unroll
        for (int k = 0; k < 64; ++k) o += hs[k] * W2[k * 8 + tid];
        out[g * 8 + tid] = o;
    }
}

// ---------------- host side ----------------

static inline void build_csr(const int* ei, const float* vals, int* rp, int2* edge,
                             int* bsum, hipStream_t stream) {
    const int EB = (E_NNZ + 255) / 256;
    const int NB1024 = (N_SIMP + 1023) / 1024;
    const int NB256 = (N_SIMP + 255) / 256;
    (void)hipMemsetAsync(rp, 0, (N_SIMP + 1) * sizeof(int), stream);
    hist_kernel<<<EB, 256, 0, stream>>>(ei, rp);
    scan_block_kernel<<<NB1024, 256, 0, stream>>>(rp, bsum, N_SIMP);
    scan_top_kernel<<<1, 64, 0, stream>>>(bsum, NB1024);
    add_off_kernel<<<NB256, 256, 0, stream>>>(rp, bsum);
    scatter_kernel<<<EB, 256, 0, stream>>>(ei, vals, rp, edge);
}

extern "C" void kernel_launch(void* const* d_in, const int* in_sizes, int n_in,
                              void* d_out, int out_size, void* d_ws, size_t ws_size,
                              hipStream_t stream) {
    const float* x     = (const float*)d_in[0];
    const int*   li    = (const int*)d_in[1];
    const float* lv    = (const float*)d_in[2];
    const int*   ui    = (const int*)d_in[3];
    const float* uv    = (const float*)d_in[4];
    const int*   bidx  = (const int*)d_in[5];
    const float* l0_Wl = (const float*)d_in[6];
    const float* l0_Wu = (const float*)d_in[8];
    const float* l0_Wh = (const float*)d_in[10];
    const float* l0_bh = (const float*)d_in[11];
    const float* l0_bl = (const float*)d_in[7];
    const float* l0_bu = (const float*)d_in[9];
    const float* l1_Wl = (const float*)d_in[12];
    const float* l1_bl = (const float*)d_in[13];
    const float* l1_Wu = (const float*)d_in[14];
    const float* l1_bu = (const float*)d_in[15];
    const float* l1_Wh = (const float*)d_in[16];
    const float* l1_bh = (const float*)d_in[17];
    const float* bn0_g = (const float*)d_in[18];
    const float* bn0_b = (const float*)d_in[19];
    const float* bn1_g = (const float*)d_in[20];
    const float* bn1_b = (const float*)d_in[21];
    const float* mW1   = (const float*)d_in[22];
    const float* mb1   = (const float*)d_in[23];
    const float* mW2   = (const float*)d_in[24];
    const float* mb2   = (const float*)d_in[25];
    float* out = (float*)d_out;

    // ---- workspace layout (total ~251.5 MB, fits 256 MiB) ----
    char* base = (char*)d_ws;
    float* z    = (float*)base;                                   // N*64 fp32 = 102,400,000
    bf16*  h0bf = (bf16*)(base + 102400000ull);                   // N*64 bf16 =  51,200,000
    bf16*  c1   = (bf16*)(base + 153600000ull);                   // N*32 bf16 =  25,600,000
    bf16*  c2   = (bf16*)(base + 179200000ull);
    bf16*  c3   = (bf16*)(base + 204800000ull);
    int2*  edge = (int2*)(base + 230400000ull);                   // E int2    =  19,200,000
    int*   rp   = (int*)(base + 249600000ull);                    // (N+1) int =   1,600,016
    int*   bsum = (int*)(base + 251200256ull);                    // 4 KB
    double* stats = (double*)(base + 251204352ull);               // 1 KB
    float* cbias  = (float*)(base + 251205376ull);                // 256 B
    float* gbuf   = (float*)(base + 251205632ull);                // 512*128*4 = 262,144

    const int MM_BLOCKS = N_SIMP / 4;       // 100,000
    const int SP_BLOCKS = N_SIMP / 8;       // 50,000

    // ---------------- layer 0 (F_IN=32 -> H=64) ----------------
    combine_bias_kernel<<<1, 64, 0, stream>>>(l0_bh, l0_bl, l0_bu, cbias);
    matmul_init_kernel<float><<<MM_BLOCKS, 256, 0, stream>>>(x, FIN, l0_Wh, cbias, z);

    // lower chain
    build_csr(li, lv, rp, edge, bsum, stream);
    spmm_csr_kernel<float><<<SP_BLOCKS, 256, 0, stream>>>(rp, edge, x, FIN, c1);
    spmm_csr_kernel<bf16><<<SP_BLOCKS, 256, 0, stream>>>(rp, edge, c1, CB, c2);
    spmm_csr_kernel<bf16><<<SP_BLOCKS, 256, 0, stream>>>(rp, edge, c2, CB, c3);
    matmul3_acc_kernel<<<MM_BLOCKS, 256, 0, stream>>>(c1, c2, c3, l0_Wl, FIN, 0, z);
    // upper chain
    build_csr(ui, uv, rp, edge, bsum, stream);
    spmm_csr_kernel<float><<<SP_BLOCKS, 256, 0, stream>>>(rp, edge, x, FIN, c1);
    spmm_csr_kernel<bf16><<<SP_BLOCKS, 256, 0, stream>>>(rp, edge, c1, CB, c2);
    spmm_csr_kernel<bf16><<<SP_BLOCKS, 256, 0, stream>>>(rp, edge, c2, CB, c3);
    matmul3_acc_kernel<<<MM_BLOCKS, 256, 0, stream>>>(c1, c2, c3, l0_Wu, FIN, 0, z);

    (void)hipMemsetAsync(stats, 0, 128 * sizeof(double), stream);
    bn_stats_kernel<<<1024, 256, 0, stream>>>(z, stats);
    bn_elu_bf16_kernel<<<2048, 256, 0, stream>>>(z, stats, bn0_g, bn0_b, h0bf);

    // ---------------- layer 1 (H=64 -> H=64) ----------------
    combine_bias_kernel<<<1, 64, 0, stream>>>(l1_bh, l1_bl, l1_bu, cbias);
    matmul_init_kernel<bf16><<<MM_BLOCKS, 256, 0, stream>>>(h0bf, HDIM, l1_Wh, cbias, z);

    // lower chains (2 column blocks of h0bf)
    build_csr(li, lv, rp, edge, bsum, stream);
    for (int p = 0; p < 2; ++p) {
        spmm_csr_kernel<bf16><<<SP_BLOCKS, 256, 0, stream>>>(rp, edge, h0bf + p * CB, HDIM, c1);
        spmm_csr_kernel<bf16><<<SP_BLOCKS, 256, 0, stream>>>(rp, edge, c1, CB, c2);
        spmm_csr_kernel<bf16><<<SP_BLOCKS, 256, 0, stream>>>(rp, edge, c2, CB, c3);
        matmul3_acc_kernel<<<MM_BLOCKS, 256, 0, stream>>>(c1, c2, c3, l1_Wl, HDIM, p * CB, z);
    }
    // upper chains
    build_csr(ui, uv, rp, edge, bsum, stream);
    for (int p = 0; p < 2; ++p) {
        spmm_csr_kernel<bf16><<<SP_BLOCKS, 256, 0, stream>>>(rp, edge, h0bf + p * CB, HDIM, c1);
        spmm_csr_kernel<bf16><<<SP_BLOCKS, 256, 0, stream>>>(rp, edge, c1, CB, c2);
        spmm_csr_kernel<bf16><<<SP_BLOCKS, 256, 0, stream>>>(rp, edge, c2, CB, c3);
        matmul3_acc_kernel<<<MM_BLOCKS, 256, 0, stream>>>(c1, c2, c3, l1_Wu, HDIM, p * CB, z);
    }

    (void)hipMemsetAsync(stats, 0, 128 * sizeof(double), stream);
    bn_stats_kernel<<<1024, 256, 0, stream>>>(z, stats);
    bn_elu_f32_kernel<<<2048, 256, 0, stream>>>(z, stats, bn1_g, bn1_b);

    // ---------------- pool + MLP ----------------
    pool_kernel<<<G_NUM, 256, 0, stream>>>(z, bidx, gbuf);
    mlp_kernel<<<G_NUM, 64, 0, stream>>>(gbuf, mW1, mb1, mW2, mb2, out);
}

// Round 6
// 3709.874 us; speedup vs baseline: 5.8075x; 1.5507x over previous
//
#include <hip/hip_runtime.h>
#include <hip/hip_bf16.h>
#include <math.h>

#define N_SIMP 400000
#define E_NNZ  2400000
#define FIN    32
#define HDIM   64
#define KAPPA  3
#define G_NUM  512
#define NOUT   8
#define BN_EPS 1e-5
#define CB     32   // chain block width (bf16)

typedef __hip_bfloat16 bf16;
typedef short s8v __attribute__((ext_vector_type(8)));   // 8 bf16 in 4 VGPRs
typedef float f4v __attribute__((ext_vector_type(4)));

__device__ __forceinline__ float elu_f(float x) {
    return x > 0.f ? x : expm1f(x);
}

// ---------------- CSR build ----------------

__global__ void hist_kernel(const int* __restrict__ ei, int* __restrict__ rp) {
    int e = blockIdx.x * 256 + threadIdx.x;
    if (e >= E_NNZ) return;
    atomicAdd(&rp[ei[e]], 1);
}

__global__ void scan_block_kernel(int* __restrict__ data, int* __restrict__ bsum, int n) {
    __shared__ int sdata[256];
    int t = threadIdx.x;
    int base = blockIdx.x * 1024 + t * 4;
    int v0 = (base + 0 < n) ? data[base + 0] : 0;
    int v1 = (base + 1 < n) ? data[base + 1] : 0;
    int v2 = (base + 2 < n) ? data[base + 2] : 0;
    int v3 = (base + 3 < n) ? data[base + 3] : 0;
    int tsum = v0 + v1 + v2 + v3;
    sdata[t] = tsum;
    __syncthreads();
    for (int off = 1; off < 256; off <<= 1) {
        int val = (t >= off) ? sdata[t - off] : 0;
        __syncthreads();
        sdata[t] += val;
        __syncthreads();
    }
    if (t == 255) bsum[blockIdx.x] = sdata[255];
    int run = sdata[t] - tsum;
    if (base + 0 < n) { data[base + 0] = run; } run += v0;
    if (base + 1 < n) { data[base + 1] = run; } run += v1;
    if (base + 2 < n) { data[base + 2] = run; } run += v2;
    if (base + 3 < n) { data[base + 3] = run; }
}

__global__ void scan_top_kernel(int* __restrict__ bsum, int nb) {
    if (threadIdx.x == 0 && blockIdx.x == 0) {
        int run = 0;
        for (int i = 0; i < nb; ++i) { int t = bsum[i]; bsum[i] = run; run += t; }
    }
}

__global__ void add_off_kernel(int* __restrict__ rp, const int* __restrict__ bsum) {
    int i = blockIdx.x * 256 + threadIdx.x;
    if (i >= N_SIMP) return;
    rp[i] += bsum[i >> 10];
}

// scatter; rp[r] advances from exclusive-start to end offset
__global__ void scatter_kernel(const int* __restrict__ ei, const float* __restrict__ vals,
                               int* __restrict__ rp, int2* __restrict__ edge) {
    int e = blockIdx.x * 256 + threadIdx.x;
    if (e >= E_NNZ) return;
    int r = ei[e];
    int pos = atomicAdd(&rp[r], 1);
    edge[pos] = make_int2(ei[E_NNZ + e], __float_as_int(vals[e]));
}

// ---------------- small prep kernels ----------------

__global__ void combine_bias_kernel(const float* __restrict__ bh,
                                    const float* __restrict__ bl,
                                    const float* __restrict__ bu,
                                    float* __restrict__ out) {
    int h = threadIdx.x;
    float acc = bh[h];
    for (int k = 0; k < KAPPA; ++k) acc += bl[k * HDIM + h] + bu[k * HDIM + h];
    out[h] = acc;
}

__global__ void f32_to_bf16_kernel(const float* __restrict__ in, bf16* __restrict__ out) {
    int idx = blockIdx.x * 256 + threadIdx.x;   // grid sized exactly N*32/256
    out[idx] = (bf16)in[idx];
}

// Wt[n*Ktot + kk] = bf16(W[srow*64 + n]), srow = (kk>>5)*rowjump + pcol + (kk&31)
__global__ void wtrans_kernel(const float* __restrict__ src, ushort* __restrict__ dst,
                              int Ktot, int rowjump, int pcol) {
    int idx = blockIdx.x * 256 + threadIdx.x;   // grid = 64*Ktot/256
    int n = idx / Ktot;
    int kk = idx - n * Ktot;
    int srow = (kk >> 5) * rowjump + pcol + (kk & 31);
    bf16 h = (bf16)src[srow * 64 + n];
    dst[idx] = *(ushort*)&h;
}

// ---------------- SpMM (CSR gather, bf16 src/dst, 32 channels) ----------------

__global__ void spmm_csr_kernel(const int* __restrict__ rp, const int2* __restrict__ edge,
                                const bf16* __restrict__ src, int src_stride,
                                bf16* __restrict__ dst) {
    int tid = threadIdx.x;
    int lane = tid & 63;
    int wv = tid >> 6;
    int sub = lane >> 5;
    int h = lane & 31;
    int row = blockIdx.x * 8 + wv * 2 + sub;
    if (row >= N_SIMP) return;
    int s = (row == 0) ? 0 : rp[row - 1];
    int e = rp[row];
    float acc = 0.f;
    int j = s;
    for (; j + 1 < e; j += 2) {
        int2 e0 = edge[j];
        int2 e1 = edge[j + 1];
        float x0 = (float)src[(size_t)e0.x * src_stride + h];
        float x1 = (float)src[(size_t)e1.x * src_stride + h];
        acc += __int_as_float(e0.y) * x0;
        acc += __int_as_float(e1.y) * x1;
    }
    if (j < e) {
        int2 e0 = edge[j];
        acc += __int_as_float(e0.y) * (float)src[(size_t)e0.x * src_stride + h];
    }
    dst[(size_t)row * CB + h] = (bf16)acc;
}

// ---------------- MFMA GEMM: z[N,64] (=bias+ / +=) A[N,K] @ W[K,64] ----------------
// A given as NCH chunks of 32 bf16 columns (ptr, stride each). Wt is bf16 [64][Ktot]
// (n-major). Block = 4 waves; wave handles 16 rows x 64 cols; grid = N/64.

template <int NCH, bool INIT>
__global__ __launch_bounds__(256) void mfma_gemm_kernel(
        const ushort* __restrict__ s0, int st0,
        const ushort* __restrict__ s1, int st1,
        const ushort* __restrict__ s2, int st2,
        const ushort* __restrict__ Wt,
        const float* __restrict__ bias,
        float* __restrict__ z) {
    const int Ktot = NCH * 32;
    int tid = threadIdx.x;
    int wv = tid >> 6, lane = tid & 63;
    int quad = lane >> 4, n = lane & 15;
    int rowbase = blockIdx.x * 64 + wv * 16;
    int arow = rowbase + n;  // A-operand row index m = lane&15

    f4v acc0 = {0.f, 0.f, 0.f, 0.f};
    f4v acc1 = {0.f, 0.f, 0.f, 0.f};
    f4v acc2 = {0.f, 0.f, 0.f, 0.f};
    f4v acc3 = {0.f, 0.f, 0.f, 0.f};

    const ushort* sps[3] = {s0, s1, s2};
    int sts[3] = {st0, st1, st2};
#pragma unroll
    for (int ch = 0; ch < NCH; ++ch) {
        s8v a = *(const s8v*)(sps[ch] + (size_t)arow * sts[ch] + quad * 8);
        const ushort* wb = Wt + ch * 32 + quad * 8;
        s8v b0 = *(const s8v*)(wb + (0 * 16 + n) * Ktot);
        s8v b1 = *(const s8v*)(wb + (1 * 16 + n) * Ktot);
        s8v b2 = *(const s8v*)(wb + (2 * 16 + n) * Ktot);
        s8v b3 = *(const s8v*)(wb + (3 * 16 + n) * Ktot);
        acc0 = __builtin_amdgcn_mfma_f32_16x16x32_bf16(a, b0, acc0, 0, 0, 0);
        acc1 = __builtin_amdgcn_mfma_f32_16x16x32_bf16(a, b1, acc1, 0, 0, 0);
        acc2 = __builtin_amdgcn_mfma_f32_16x16x32_bf16(a, b2, acc2, 0, 0, 0);
        acc3 = __builtin_amdgcn_mfma_f32_16x16x32_bf16(a, b3, acc3, 0, 0, 0);
    }
    // C/D layout: col = lane&15, row = quad*4 + reg
#pragma unroll
    for (int r = 0; r < 4; ++r) {
        int orow = rowbase + quad * 4 + r;
        float* zp = z + (size_t)orow * 64 + n;
        if (INIT) {
            zp[0]  = bias[n]      + acc0[r];
            zp[16] = bias[16 + n] + acc1[r];
            zp[32] = bias[32 + n] + acc2[r];
            zp[48] = bias[48 + n] + acc3[r];
        } else {
            zp[0]  += acc0[r];
            zp[16] += acc1[r];
            zp[32] += acc2[r];
            zp[48] += acc3[r];
        }
    }
}

// ---------------- BN / pool / MLP ----------------

__global__ void bn_stats_kernel(const float* __restrict__ z, double* __restrict__ stats) {
    __shared__ double s1[256], s2[256];
    int tid = threadIdx.x;
    const long long total = (long long)N_SIMP * HDIM;
    double sum = 0.0, sq = 0.0;
    for (long long idx = (long long)blockIdx.x * 256 + tid; idx < total;
         idx += (long long)gridDim.x * 256) {
        float v = z[idx];
        sum += v;
        sq += (double)v * v;
    }
    s1[tid] = sum; s2[tid] = sq;
    __syncthreads();
    if (tid < 64) {
        double a = s1[tid] + s1[tid + 64] + s1[tid + 128] + s1[tid + 192];
        double b = s2[tid] + s2[tid + 64] + s2[tid + 128] + s2[tid + 192];
        atomicAdd(&stats[tid], a);
        atomicAdd(&stats[64 + tid], b);
    }
}

__global__ void bn_elu_bf16_kernel(const float* __restrict__ z, const double* __restrict__ stats,
                                   const float* __restrict__ gamma, const float* __restrict__ beta,
                                   bf16* __restrict__ out) {
    __shared__ float scale_s[64], shift_s[64];
    int tid = threadIdx.x;
    if (tid < 64) {
        double mean = stats[tid] / (double)N_SIMP;
        double var = stats[64 + tid] / (double)N_SIMP - mean * mean;
        double sc = (double)gamma[tid] / sqrt(var + BN_EPS);
        scale_s[tid] = (float)sc;
        shift_s[tid] = (float)((double)beta[tid] - mean * sc);
    }
    __syncthreads();
    const long long total = (long long)N_SIMP * HDIM;
    for (long long idx = (long long)blockIdx.x * 256 + tid; idx < total;
         idx += (long long)gridDim.x * 256) {
        int h = (int)(idx & 63);
        out[idx] = (bf16)elu_f(z[idx] * scale_s[h] + shift_s[h]);
    }
}

__global__ void bn_elu_f32_kernel(float* __restrict__ z, const double* __restrict__ stats,
                                  const float* __restrict__ gamma, const float* __restrict__ beta) {
    __shared__ float scale_s[64], shift_s[64];
    int tid = threadIdx.x;
    if (tid < 64) {
        double mean = stats[tid] / (double)N_SIMP;
        double var = stats[64 + tid] / (double)N_SIMP - mean * mean;
        double sc = (double)gamma[tid] / sqrt(var + BN_EPS);
        scale_s[tid] = (float)sc;
        shift_s[tid] = (float)((double)beta[tid] - mean * sc);
    }
    __syncthreads();
    const long long total = (long long)N_SIMP * HDIM;
    for (long long idx = (long long)blockIdx.x * 256 + tid; idx < total;
         idx += (long long)gridDim.x * 256) {
        int h = (int)(idx & 63);
        z[idx] = elu_f(z[idx] * scale_s[h] + shift_s[h]);
    }
}

__global__ void pool_kernel(const float* __restrict__ hbuf, const int* __restrict__ bidx,
                            float* __restrict__ gbuf) {
    __shared__ float smax[256], ssum[256];
    int g = blockIdx.x;
    int tid = threadIdx.x;
    int lo = 0, hi = N_SIMP;
    while (lo < hi) { int mid = (lo + hi) >> 1; if (bidx[mid] < g) lo = mid + 1; else hi = mid; }
    int start = lo;
    hi = N_SIMP;
    while (lo < hi) { int mid = (lo + hi) >> 1; if (bidx[mid] < g + 1) lo = mid + 1; else hi = mid; }
    int end = lo;
    int h = tid & 63, rep = tid >> 6;
    float mx = -INFINITY, sm = 0.f;
    for (int i = start + rep; i < end; i += 4) {
        float v = hbuf[(size_t)i * HDIM + h];
        mx = fmaxf(mx, v);
        sm += v;
    }
    smax[tid] = mx; ssum[tid] = sm;
    __syncthreads();
    if (tid < 64) {
        float m = fmaxf(fmaxf(smax[tid], smax[tid + 64]), fmaxf(smax[tid + 128], smax[tid + 192]));
        float s = ssum[tid] + ssum[tid + 64] + ssum[tid + 128] + ssum[tid + 192];
        int cnt = end - start;
        float mean = s / fmaxf((float)cnt, 1.f);
        gbuf[g * 128 + tid] = elu_f(m);
        gbuf[g * 128 + 64 + tid] = elu_f(mean);
    }
}

__global__ void mlp_kernel(const float* __restrict__ gbuf, const float* __restrict__ W1,
                           const float* __restrict__ b1, const float* __restrict__ W2,
                           const float* __restrict__ b2, float* __restrict__ out) {
    __shared__ float gs[128];
    __shared__ float hs[64];
    int g = blockIdx.x, tid = threadIdx.x;
    gs[tid] = gbuf[g * 128 + tid];
    gs[64 + tid] = gbuf[g * 128 + 64 + tid];
    __syncthreads();
    float acc = b1[tid];
#pragma unroll
    for (int k = 0; k < 128; ++k) acc += gs[k] * W1[k * 64 + tid];
    hs[tid] = fmaxf(acc, 0.f);
    __syncthreads();
    if (tid < 8) {
        float o = b2[tid];
#pragma unroll
        for (int k = 0; k < 64; ++k) o += hs[k] * W2[k * 8 + tid];
        out[g * 8 + tid] = o;
    }
}

// ---------------- host side ----------------

static inline void build_csr(const int* ei, const float* vals, int* rp, int2* edge,
                             int* bsum, hipStream_t stream) {
    const int EB = (E_NNZ + 255) / 256;
    const int NB1024 = (N_SIMP + 1023) / 1024;
    const int NB256 = (N_SIMP + 255) / 256;
    (void)hipMemsetAsync(rp, 0, (N_SIMP + 1) * sizeof(int), stream);
    hist_kernel<<<EB, 256, 0, stream>>>(ei, rp);
    scan_block_kernel<<<NB1024, 256, 0, stream>>>(rp, bsum, N_SIMP);
    scan_top_kernel<<<1, 64, 0, stream>>>(bsum, NB1024);
    add_off_kernel<<<NB256, 256, 0, stream>>>(rp, bsum);
    scatter_kernel<<<EB, 256, 0, stream>>>(ei, vals, rp, edge);
}

extern "C" void kernel_launch(void* const* d_in, const int* in_sizes, int n_in,
                              void* d_out, int out_size, void* d_ws, size_t ws_size,
                              hipStream_t stream) {
    const float* x     = (const float*)d_in[0];
    const int*   li    = (const int*)d_in[1];
    const float* lv    = (const float*)d_in[2];
    const int*   ui    = (const int*)d_in[3];
    const float* uv    = (const float*)d_in[4];
    const int*   bidx  = (const int*)d_in[5];
    const float* l0_Wl = (const float*)d_in[6];
    const float* l0_bl = (const float*)d_in[7];
    const float* l0_Wu = (const float*)d_in[8];
    const float* l0_bu = (const float*)d_in[9];
    const float* l0_Wh = (const float*)d_in[10];
    const float* l0_bh = (const float*)d_in[11];
    const float* l1_Wl = (const float*)d_in[12];
    const float* l1_bl = (const float*)d_in[13];
    const float* l1_Wu = (const float*)d_in[14];
    const float* l1_bu = (const float*)d_in[15];
    const float* l1_Wh = (const float*)d_in[16];
    const float* l1_bh = (const float*)d_in[17];
    const float* bn0_g = (const float*)d_in[18];
    const float* bn0_b = (const float*)d_in[19];
    const float* bn1_g = (const float*)d_in[20];
    const float* bn1_b = (const float*)d_in[21];
    const float* mW1   = (const float*)d_in[22];
    const float* mb1   = (const float*)d_in[23];
    const float* mW2   = (const float*)d_in[24];
    const float* mb2   = (const float*)d_in[25];
    float* out = (float*)d_out;

    // ---- workspace layout (total ~251.6 MB, fits 256 MiB) ----
    char* base = (char*)d_ws;
    float* z    = (float*)base;                                   // 102,400,000
    bf16*  h0bf = (bf16*)(base + 102400000ull);                   //  51,200,000
    bf16*  c1   = (bf16*)(base + 153600000ull);                   //  25,600,000
    bf16*  c2   = (bf16*)(base + 179200000ull);
    bf16*  c3   = (bf16*)(base + 204800000ull);
    int2*  edge = (int2*)(base + 230400000ull);                   //  19,200,000
    int*   rp   = (int*)(base + 249600000ull);                    //   1,600,016
    int*   bsum = (int*)(base + 251200256ull);                    //   4 KB
    double* stats = (double*)(base + 251204352ull);               //   1 KB
    float* cbias  = (float*)(base + 251205376ull);                //   256 B
    float* gbuf   = (float*)(base + 251205632ull);                //   262,144
    ushort* wt    = (ushort*)(base + 251467776ull);               //   86 KB

    // chain scratch inside h0bf region (free during layer 0)
    bf16* d1 = h0bf;
    bf16* d2 = h0bf + (size_t)N_SIMP * CB;

    // weight-transpose sub-buffers (bf16 elements)
    ushort* wt_l0h  = wt;            // 64x32
    ushort* wt_l1h  = wt + 2048;     // 64x64
    ushort* wt_l0l  = wt + 6144;     // 64x96
    ushort* wt_l0u  = wt + 12288;
    ushort* wt_l1l0 = wt + 18432;
    ushort* wt_l1l1 = wt + 24576;
    ushort* wt_l1u0 = wt + 30720;
    ushort* wt_l1u1 = wt + 36864;

    const int SP_BLOCKS = N_SIMP / 8;    // 50,000
    const int MF_BLOCKS = N_SIMP / 64;   // 6,250

    // ---- prep: weight transposes + x->bf16 ----
    wtrans_kernel<<<8, 256, 0, stream>>>(l0_Wh, wt_l0h, 32, 32, 0);
    wtrans_kernel<<<16, 256, 0, stream>>>(l1_Wh, wt_l1h, 64, 32, 0);
    wtrans_kernel<<<24, 256, 0, stream>>>(l0_Wl, wt_l0l, 96, 32, 0);
    wtrans_kernel<<<24, 256, 0, stream>>>(l0_Wu, wt_l0u, 96, 32, 0);
    wtrans_kernel<<<24, 256, 0, stream>>>(l1_Wl, wt_l1l0, 96, 64, 0);
    wtrans_kernel<<<24, 256, 0, stream>>>(l1_Wl, wt_l1l1, 96, 64, 32);
    wtrans_kernel<<<24, 256, 0, stream>>>(l1_Wu, wt_l1u0, 96, 64, 0);
    wtrans_kernel<<<24, 256, 0, stream>>>(l1_Wu, wt_l1u1, 96, 64, 32);
    f32_to_bf16_kernel<<<N_SIMP * 32 / 256, 256, 0, stream>>>(x, c1);  // c1 = x in bf16

    const ushort* xbf = (const ushort*)c1;
    const ushort* h0u = (const ushort*)h0bf;

    // ---------------- layer 0 (F_IN=32 -> H=64) ----------------
    combine_bias_kernel<<<1, 64, 0, stream>>>(l0_bh, l0_bl, l0_bu, cbias);
    mfma_gemm_kernel<1, true><<<MF_BLOCKS, 256, 0, stream>>>(
        xbf, 32, nullptr, 0, nullptr, 0, wt_l0h, cbias, z);

    // lower chain: c1 -> d1 -> d2 -> c2
    build_csr(li, lv, rp, edge, bsum, stream);
    spmm_csr_kernel<<<SP_BLOCKS, 256, 0, stream>>>(rp, edge, c1, 32, d1);
    spmm_csr_kernel<<<SP_BLOCKS, 256, 0, stream>>>(rp, edge, d1, 32, d2);
    spmm_csr_kernel<<<SP_BLOCKS, 256, 0, stream>>>(rp, edge, d2, 32, c2);
    mfma_gemm_kernel<3, false><<<MF_BLOCKS, 256, 0, stream>>>(
        (const ushort*)d1, 32, (const ushort*)d2, 32, (const ushort*)c2, 32,
        wt_l0l, nullptr, z);
    // upper chain
    build_csr(ui, uv, rp, edge, bsum, stream);
    spmm_csr_kernel<<<SP_BLOCKS, 256, 0, stream>>>(rp, edge, c1, 32, d1);
    spmm_csr_kernel<<<SP_BLOCKS, 256, 0, stream>>>(rp, edge, d1, 32, d2);
    spmm_csr_kernel<<<SP_BLOCKS, 256, 0, stream>>>(rp, edge, d2, 32, c2);
    mfma_gemm_kernel<3, false><<<MF_BLOCKS, 256, 0, stream>>>(
        (const ushort*)d1, 32, (const ushort*)d2, 32, (const ushort*)c2, 32,
        wt_l0u, nullptr, z);

    (void)hipMemsetAsync(stats, 0, 128 * sizeof(double), stream);
    bn_stats_kernel<<<1024, 256, 0, stream>>>(z, stats);
    bn_elu_bf16_kernel<<<2048, 256, 0, stream>>>(z, stats, bn0_g, bn0_b, h0bf);

    // ---------------- layer 1 (H=64 -> H=64) ----------------
    combine_bias_kernel<<<1, 64, 0, stream>>>(l1_bh, l1_bl, l1_bu, cbias);
    mfma_gemm_kernel<2, true><<<MF_BLOCKS, 256, 0, stream>>>(
        h0u, 64, h0u + 32, 64, nullptr, 0, wt_l1h, cbias, z);

    build_csr(li, lv, rp, edge, bsum, stream);
    for (int p = 0; p < 2; ++p) {
        spmm_csr_kernel<<<SP_BLOCKS, 256, 0, stream>>>(rp, edge, h0bf + p * CB, 64, c1);
        spmm_csr_kernel<<<SP_BLOCKS, 256, 0, stream>>>(rp, edge, c1, 32, c2);
        spmm_csr_kernel<<<SP_BLOCKS, 256, 0, stream>>>(rp, edge, c2, 32, c3);
        mfma_gemm_kernel<3, false><<<MF_BLOCKS, 256, 0, stream>>>(
            (const ushort*)c1, 32, (const ushort*)c2, 32, (const ushort*)c3, 32,
            p ? wt_l1l1 : wt_l1l0, nullptr, z);
    }
    build_csr(ui, uv, rp, edge, bsum, stream);
    for (int p = 0; p < 2; ++p) {
        spmm_csr_kernel<<<SP_BLOCKS, 256, 0, stream>>>(rp, edge, h0bf + p * CB, 64, c1);
        spmm_csr_kernel<<<SP_BLOCKS, 256, 0, stream>>>(rp, edge, c1, 32, c2);
        spmm_csr_kernel<<<SP_BLOCKS, 256, 0, stream>>>(rp, edge, c2, 32, c3);
        mfma_gemm_kernel<3, false><<<MF_BLOCKS, 256, 0, stream>>>(
            (const ushort*)c1, 32, (const ushort*)c2, 32, (const ushort*)c3, 32,
            p ? wt_l1u1 : wt_l1u0, nullptr, z);
    }

    (void)hipMemsetAsync(stats, 0, 128 * sizeof(double), stream);
    bn_stats_kernel<<<1024, 256, 0, stream>>>(z, stats);
    bn_elu_f32_kernel<<<2048, 256, 0, stream>>>(z, stats, bn1_g, bn1_b);

    // ---------------- pool + MLP ----------------
    pool_kernel<<<G_NUM, 256, 0, stream>>>(z, bidx, gbuf);
    mlp_kernel<<<G_NUM, 64, 0, stream>>>(gbuf, mW1, mb1, mW2, mb2, out);
}

// Round 7
// 3132.901 us; speedup vs baseline: 6.8771x; 1.1842x over previous
//
#include <hip/hip_runtime.h>
#include <hip/hip_bf16.h>
#include <math.h>

#define N_SIMP 400000
#define E_NNZ  2400000
#define FIN    32
#define HDIM   64
#define KAPPA  3
#define G_NUM  512
#define NOUT   8
#define BN_EPS 1e-5
#define CB     32   // chain block width (bf16)

typedef __hip_bfloat16 bf16;
typedef short s8v __attribute__((ext_vector_type(8)));   // 8 bf16 in 4 VGPRs
typedef float f4v __attribute__((ext_vector_type(4)));

__device__ __forceinline__ float elu_f(float x) {
    return x > 0.f ? x : expm1f(x);
}

// ---------------- CSR build ----------------

__global__ void hist_kernel(const int* __restrict__ ei, int* __restrict__ rp) {
    int e = blockIdx.x * 256 + threadIdx.x;
    if (e >= E_NNZ) return;
    atomicAdd(&rp[ei[e]], 1);
}

__global__ void scan_block_kernel(int* __restrict__ data, int* __restrict__ bsum, int n) {
    __shared__ int sdata[256];
    int t = threadIdx.x;
    int base = blockIdx.x * 1024 + t * 4;
    int v0 = (base + 0 < n) ? data[base + 0] : 0;
    int v1 = (base + 1 < n) ? data[base + 1] : 0;
    int v2 = (base + 2 < n) ? data[base + 2] : 0;
    int v3 = (base + 3 < n) ? data[base + 3] : 0;
    int tsum = v0 + v1 + v2 + v3;
    sdata[t] = tsum;
    __syncthreads();
    for (int off = 1; off < 256; off <<= 1) {
        int val = (t >= off) ? sdata[t - off] : 0;
        __syncthreads();
        sdata[t] += val;
        __syncthreads();
    }
    if (t == 255) bsum[blockIdx.x] = sdata[255];
    int run = sdata[t] - tsum;
    if (base + 0 < n) { data[base + 0] = run; } run += v0;
    if (base + 1 < n) { data[base + 1] = run; } run += v1;
    if (base + 2 < n) { data[base + 2] = run; } run += v2;
    if (base + 3 < n) { data[base + 3] = run; }
}

__global__ void scan_top_kernel(int* __restrict__ bsum, int nb) {
    if (threadIdx.x == 0 && blockIdx.x == 0) {
        int run = 0;
        for (int i = 0; i < nb; ++i) { int t = bsum[i]; bsum[i] = run; run += t; }
    }
}

__global__ void add_off_kernel(int* __restrict__ rp, const int* __restrict__ bsum) {
    int i = blockIdx.x * 256 + threadIdx.x;
    if (i >= N_SIMP) return;
    rp[i] += bsum[i >> 10];
}

// scatter; rp[r] advances from exclusive-start to end offset
__global__ void scatter_kernel(const int* __restrict__ ei, const float* __restrict__ vals,
                               int* __restrict__ rp, int2* __restrict__ edge) {
    int e = blockIdx.x * 256 + threadIdx.x;
    if (e >= E_NNZ) return;
    int r = ei[e];
    int pos = atomicAdd(&rp[r], 1);
    edge[pos] = make_int2(ei[E_NNZ + e], __float_as_int(vals[e]));
}

// ---------------- small prep kernels ----------------

__global__ void combine_bias_kernel(const float* __restrict__ bh,
                                    const float* __restrict__ bl,
                                    const float* __restrict__ bu,
                                    float* __restrict__ out) {
    int h = threadIdx.x;
    float acc = bh[h];
    for (int k = 0; k < KAPPA; ++k) acc += bl[k * HDIM + h] + bu[k * HDIM + h];
    out[h] = acc;
}

__global__ void f32_to_bf16_kernel(const float* __restrict__ in, bf16* __restrict__ out) {
    int idx = blockIdx.x * 256 + threadIdx.x;   // grid sized exactly N*32/256
    out[idx] = (bf16)in[idx];
}

// Wt[n*Ktot + kk] = bf16(W[srow*64 + n]), srow = (kk>>5)*rowjump + pcol + (kk&31)
__global__ void wtrans_kernel(const float* __restrict__ src, ushort* __restrict__ dst,
                              int Ktot, int rowjump, int pcol) {
    int idx = blockIdx.x * 256 + threadIdx.x;   // grid = 64*Ktot/256
    int n = idx / Ktot;
    int kk = idx - n * Ktot;
    int srow = (kk >> 5) * rowjump + pcol + (kk & 31);
    bf16 h = (bf16)src[srow * 64 + n];
    dst[idx] = *(ushort*)&h;
}

// ---------------- SpMM (CSR gather, bf16 src/dst, 32 channels) ----------------
// 2 rows/wave, 8 rows/block. Unroll-4 for gather-latency hiding.

__global__ void spmm_csr_kernel(const int* __restrict__ rp, const int2* __restrict__ edge,
                                const bf16* __restrict__ src, int src_stride,
                                bf16* __restrict__ dst) {
    int tid = threadIdx.x;
    int lane = tid & 63;
    int wv = tid >> 6;
    int sub = lane >> 5;
    int h = lane & 31;
    int row = blockIdx.x * 8 + wv * 2 + sub;
    if (row >= N_SIMP) return;
    int s = (row == 0) ? 0 : rp[row - 1];
    int e = rp[row];
    float a0 = 0.f, a1 = 0.f, a2 = 0.f, a3 = 0.f;
    int j = s;
    for (; j + 3 < e; j += 4) {
        int2 e0 = edge[j];
        int2 e1 = edge[j + 1];
        int2 e2 = edge[j + 2];
        int2 e3 = edge[j + 3];
        float x0 = (float)src[(size_t)e0.x * src_stride + h];
        float x1 = (float)src[(size_t)e1.x * src_stride + h];
        float x2 = (float)src[(size_t)e2.x * src_stride + h];
        float x3 = (float)src[(size_t)e3.x * src_stride + h];
        a0 += __int_as_float(e0.y) * x0;
        a1 += __int_as_float(e1.y) * x1;
        a2 += __int_as_float(e2.y) * x2;
        a3 += __int_as_float(e3.y) * x3;
    }
    for (; j < e; ++j) {
        int2 e0 = edge[j];
        a0 += __int_as_float(e0.y) * (float)src[(size_t)e0.x * src_stride + h];
    }
    dst[(size_t)row * CB + h] = (bf16)((a0 + a1) + (a2 + a3));
}

// ---------------- MFMA GEMM: z[N,64] (=bias+ / +=) A[N, NCH*32] @ W ----------------
// A as up to 2 chunks of 32 bf16 cols (ptr, stride). Wt bf16 [64][Kstride] n-major.
// Block = 4 waves; wave = 16 rows x 64 cols; grid = N/64.

template <int NCH, bool INIT>
__global__ __launch_bounds__(256) void mfma_gemm_kernel(
        const ushort* __restrict__ s0, int st0,
        const ushort* __restrict__ s1, int st1,
        const ushort* __restrict__ Wt, int Kstride,
        const float* __restrict__ bias,
        float* __restrict__ z) {
    int tid = threadIdx.x;
    int wv = tid >> 6, lane = tid & 63;
    int quad = lane >> 4, n = lane & 15;
    int rowbase = blockIdx.x * 64 + wv * 16;
    int arow = rowbase + n;  // A-operand row m = lane&15

    f4v acc0 = {0.f, 0.f, 0.f, 0.f};
    f4v acc1 = {0.f, 0.f, 0.f, 0.f};
    f4v acc2 = {0.f, 0.f, 0.f, 0.f};
    f4v acc3 = {0.f, 0.f, 0.f, 0.f};

#pragma unroll
    for (int ch = 0; ch < NCH; ++ch) {
        const ushort* sp = (ch == 0) ? s0 : s1;
        int st = (ch == 0) ? st0 : st1;
        s8v a = *(const s8v*)(sp + (size_t)arow * st + quad * 8);
        const ushort* wb = Wt + ch * 32 + quad * 8;
        s8v b0 = *(const s8v*)(wb + (size_t)(0 * 16 + n) * Kstride);
        s8v b1 = *(const s8v*)(wb + (size_t)(1 * 16 + n) * Kstride);
        s8v b2 = *(const s8v*)(wb + (size_t)(2 * 16 + n) * Kstride);
        s8v b3 = *(const s8v*)(wb + (size_t)(3 * 16 + n) * Kstride);
        acc0 = __builtin_amdgcn_mfma_f32_16x16x32_bf16(a, b0, acc0, 0, 0, 0);
        acc1 = __builtin_amdgcn_mfma_f32_16x16x32_bf16(a, b1, acc1, 0, 0, 0);
        acc2 = __builtin_amdgcn_mfma_f32_16x16x32_bf16(a, b2, acc2, 0, 0, 0);
        acc3 = __builtin_amdgcn_mfma_f32_16x16x32_bf16(a, b3, acc3, 0, 0, 0);
    }
    // C/D layout: col = lane&15, row = quad*4 + reg
#pragma unroll
    for (int r = 0; r < 4; ++r) {
        int orow = rowbase + quad * 4 + r;
        float* zp = z + (size_t)orow * 64 + n;
        if (INIT) {
            zp[0]  = bias[n]      + acc0[r];
            zp[16] = bias[16 + n] + acc1[r];
            zp[32] = bias[32 + n] + acc2[r];
            zp[48] = bias[48 + n] + acc3[r];
        } else {
            zp[0]  += acc0[r];
            zp[16] += acc1[r];
            zp[32] += acc2[r];
            zp[48] += acc3[r];
        }
    }
}

// ---------------- BN / pool / MLP ----------------

__global__ void bn_stats_kernel(const float* __restrict__ z, double* __restrict__ stats) {
    __shared__ double s1[256], s2[256];
    int tid = threadIdx.x;
    const long long total = (long long)N_SIMP * HDIM;
    double sum = 0.0, sq = 0.0;
    for (long long idx = (long long)blockIdx.x * 256 + tid; idx < total;
         idx += (long long)gridDim.x * 256) {
        float v = z[idx];
        sum += v;
        sq += (double)v * v;
    }
    s1[tid] = sum; s2[tid] = sq;
    __syncthreads();
    if (tid < 64) {
        double a = s1[tid] + s1[tid + 64] + s1[tid + 128] + s1[tid + 192];
        double b = s2[tid] + s2[tid + 64] + s2[tid + 128] + s2[tid + 192];
        atomicAdd(&stats[tid], a);
        atomicAdd(&stats[64 + tid], b);
    }
}

__global__ void bn_elu_bf16_kernel(const float* __restrict__ z, const double* __restrict__ stats,
                                   const float* __restrict__ gamma, const float* __restrict__ beta,
                                   bf16* __restrict__ out) {
    __shared__ float scale_s[64], shift_s[64];
    int tid = threadIdx.x;
    if (tid < 64) {
        double mean = stats[tid] / (double)N_SIMP;
        double var = stats[64 + tid] / (double)N_SIMP - mean * mean;
        double sc = (double)gamma[tid] / sqrt(var + BN_EPS);
        scale_s[tid] = (float)sc;
        shift_s[tid] = (float)((double)beta[tid] - mean * sc);
    }
    __syncthreads();
    const long long total = (long long)N_SIMP * HDIM;
    for (long long idx = (long long)blockIdx.x * 256 + tid; idx < total;
         idx += (long long)gridDim.x * 256) {
        int h = (int)(idx & 63);
        out[idx] = (bf16)elu_f(z[idx] * scale_s[h] + shift_s[h]);
    }
}

__global__ void bn_elu_f32_kernel(float* __restrict__ z, const double* __restrict__ stats,
                                  const float* __restrict__ gamma, const float* __restrict__ beta) {
    __shared__ float scale_s[64], shift_s[64];
    int tid = threadIdx.x;
    if (tid < 64) {
        double mean = stats[tid] / (double)N_SIMP;
        double var = stats[64 + tid] / (double)N_SIMP - mean * mean;
        double sc = (double)gamma[tid] / sqrt(var + BN_EPS);
        scale_s[tid] = (float)sc;
        shift_s[tid] = (float)((double)beta[tid] - mean * sc);
    }
    __syncthreads();
    const long long total = (long long)N_SIMP * HDIM;
    for (long long idx = (long long)blockIdx.x * 256 + tid; idx < total;
         idx += (long long)gridDim.x * 256) {
        int h = (int)(idx & 63);
        z[idx] = elu_f(z[idx] * scale_s[h] + shift_s[h]);
    }
}

__global__ void pool_kernel(const float* __restrict__ hbuf, const int* __restrict__ bidx,
                            float* __restrict__ gbuf) {
    __shared__ float smax[256], ssum[256];
    int g = blockIdx.x;
    int tid = threadIdx.x;
    int lo = 0, hi = N_SIMP;
    while (lo < hi) { int mid = (lo + hi) >> 1; if (bidx[mid] < g) lo = mid + 1; else hi = mid; }
    int start = lo;
    hi = N_SIMP;
    while (lo < hi) { int mid = (lo + hi) >> 1; if (bidx[mid] < g + 1) lo = mid + 1; else hi = mid; }
    int end = lo;
    int h = tid & 63, rep = tid >> 6;
    float mx = -INFINITY, sm = 0.f;
    for (int i = start + rep; i < end; i += 4) {
        float v = hbuf[(size_t)i * HDIM + h];
        mx = fmaxf(mx, v);
        sm += v;
    }
    smax[tid] = mx; ssum[tid] = sm;
    __syncthreads();
    if (tid < 64) {
        float m = fmaxf(fmaxf(smax[tid], smax[tid + 64]), fmaxf(smax[tid + 128], smax[tid + 192]));
        float s = ssum[tid] + ssum[tid + 64] + ssum[tid + 128] + ssum[tid + 192];
        int cnt = end - start;
        float mean = s / fmaxf((float)cnt, 1.f);
        gbuf[g * 128 + tid] = elu_f(m);
        gbuf[g * 128 + 64 + tid] = elu_f(mean);
    }
}

__global__ void mlp_kernel(const float* __restrict__ gbuf, const float* __restrict__ W1,
                           const float* __restrict__ b1, const float* __restrict__ W2,
                           const float* __restrict__ b2, float* __restrict__ out) {
    __shared__ float gs[128];
    __shared__ float hs[64];
    int g = blockIdx.x, tid = threadIdx.x;
    gs[tid] = gbuf[g * 128 + tid];
    gs[64 + tid] = gbuf[g * 128 + 64 + tid];
    __syncthreads();
    float acc = b1[tid];
#pragma unroll
    for (int k = 0; k < 128; ++k) acc += gs[k] * W1[k * 64 + tid];
    hs[tid] = fmaxf(acc, 0.f);
    __syncthreads();
    if (tid < 8) {
        float o = b2[tid];
#pragma unroll
        for (int k = 0; k < 64; ++k) o += hs[k] * W2[k * 8 + tid];
        out[g * 8 + tid] = o;
    }
}

// ---------------- host side ----------------

static inline void build_csr(const int* ei, const float* vals, int* rp, int2* edge,
                             int* bsum, hipStream_t stream) {
    const int EB = (E_NNZ + 255) / 256;
    const int NB1024 = (N_SIMP + 1023) / 1024;
    const int NB256 = (N_SIMP + 255) / 256;
    (void)hipMemsetAsync(rp, 0, (N_SIMP + 1) * sizeof(int), stream);
    hist_kernel<<<EB, 256, 0, stream>>>(ei, rp);
    scan_block_kernel<<<NB1024, 256, 0, stream>>>(rp, bsum, N_SIMP);
    scan_top_kernel<<<1, 64, 0, stream>>>(bsum, NB1024);
    add_off_kernel<<<NB256, 256, 0, stream>>>(rp, bsum);
    scatter_kernel<<<EB, 256, 0, stream>>>(ei, vals, rp, edge);
}

extern "C" void kernel_launch(void* const* d_in, const int* in_sizes, int n_in,
                              void* d_out, int out_size, void* d_ws, size_t ws_size,
                              hipStream_t stream) {
    const float* x     = (const float*)d_in[0];
    const int*   li    = (const int*)d_in[1];
    const float* lv    = (const float*)d_in[2];
    const int*   ui    = (const int*)d_in[3];
    const float* uv    = (const float*)d_in[4];
    const int*   bidx  = (const int*)d_in[5];
    const float* l0_Wl = (const float*)d_in[6];
    const float* l0_bl = (const float*)d_in[7];
    const float* l0_Wu = (const float*)d_in[8];
    const float* l0_bu = (const float*)d_in[9];
    const float* l0_Wh = (const float*)d_in[10];
    const float* l0_bh = (const float*)d_in[11];
    const float* l1_Wl = (const float*)d_in[12];
    const float* l1_bl = (const float*)d_in[13];
    const float* l1_Wu = (const float*)d_in[14];
    const float* l1_bu = (const float*)d_in[15];
    const float* l1_Wh = (const float*)d_in[16];
    const float* l1_bh = (const float*)d_in[17];
    const float* bn0_g = (const float*)d_in[18];
    const float* bn0_b = (const float*)d_in[19];
    const float* bn1_g = (const float*)d_in[20];
    const float* bn1_b = (const float*)d_in[21];
    const float* mW1   = (const float*)d_in[22];
    const float* mb1   = (const float*)d_in[23];
    const float* mW2   = (const float*)d_in[24];
    const float* mb2   = (const float*)d_in[25];
    float* out = (float*)d_out;

    // ---- workspace layout (total ~246.8 MB, fits 256 MiB) ----
    char* base = (char*)d_ws;
    float* z     = (float*)base;                                  // 102,400,000
    bf16*  h0bf  = (bf16*)(base + 102400000ull);                  //  51,200,000
    bf16*  c1    = (bf16*)(base + 153600000ull);                  //  25,600,000
    bf16*  c2    = (bf16*)(base + 179200000ull);                  //  25,600,000
    int2*  edgeL = (int2*)(base + 204800000ull);                  //  19,200,000
    int2*  edgeU = (int2*)(base + 224000000ull);                  //  19,200,000
    int*   rpL   = (int*)(base + 243200000ull);                   //   1,600,032 (padded)
    int*   rpU   = (int*)(base + 244800032ull);                   //   1,600,032
    int*   bsum  = (int*)(base + 246400064ull);                   //   4 KB
    double* stats = (double*)(base + 246404160ull);               //   1 KB
    float* cbias  = (float*)(base + 246405184ull);                //   256 B
    float* gbuf   = (float*)(base + 246405440ull);                //   262,144
    ushort* wt    = (ushort*)(base + 246667584ull);               //   86,016

    // chain scratch inside h0bf region (free during layer 0)
    bf16* d1 = h0bf;
    bf16* d2 = h0bf + (size_t)N_SIMP * CB;

    // weight-transpose sub-buffers (ushort elements)
    ushort* wt_l0h  = wt;            // 64x32
    ushort* wt_l1h  = wt + 2048;     // 64x64
    ushort* wt_l0l  = wt + 6144;     // 64x96
    ushort* wt_l0u  = wt + 12288;
    ushort* wt_l1l0 = wt + 18432;
    ushort* wt_l1l1 = wt + 24576;
    ushort* wt_l1u0 = wt + 30720;
    ushort* wt_l1u1 = wt + 36864;

    const int SP_BLOCKS = N_SIMP / 8;    // 50,000
    const int MF_BLOCKS = N_SIMP / 64;   // 6,250

    // ---- prep: weight transposes + x->bf16 ----
    wtrans_kernel<<<8, 256, 0, stream>>>(l0_Wh, wt_l0h, 32, 32, 0);
    wtrans_kernel<<<16, 256, 0, stream>>>(l1_Wh, wt_l1h, 64, 32, 0);
    wtrans_kernel<<<24, 256, 0, stream>>>(l0_Wl, wt_l0l, 96, 32, 0);
    wtrans_kernel<<<24, 256, 0, stream>>>(l0_Wu, wt_l0u, 96, 32, 0);
    wtrans_kernel<<<24, 256, 0, stream>>>(l1_Wl, wt_l1l0, 96, 64, 0);
    wtrans_kernel<<<24, 256, 0, stream>>>(l1_Wl, wt_l1l1, 96, 64, 32);
    wtrans_kernel<<<24, 256, 0, stream>>>(l1_Wu, wt_l1u0, 96, 64, 0);
    wtrans_kernel<<<24, 256, 0, stream>>>(l1_Wu, wt_l1u1, 96, 64, 32);
    f32_to_bf16_kernel<<<N_SIMP * 32 / 256, 256, 0, stream>>>(x, c1);  // c1 = x bf16

    const ushort* xbf = (const ushort*)c1;
    const ushort* h0u = (const ushort*)h0bf;

    // ---- CSR builds (once per Laplacian, persistent) ----
    build_csr(li, lv, rpL, edgeL, bsum, stream);
    build_csr(ui, uv, rpU, edgeU, bsum, stream);

    // ---------------- layer 0 (F_IN=32 -> H=64) ----------------
    combine_bias_kernel<<<1, 64, 0, stream>>>(l0_bh, l0_bl, l0_bu, cbias);
    mfma_gemm_kernel<1, true><<<MF_BLOCKS, 256, 0, stream>>>(
        xbf, 32, nullptr, 0, wt_l0h, 32, cbias, z);

    {
        const int*  rps[2]  = {rpL, rpU};
        const int2* edges[2] = {edgeL, edgeU};
        ushort*     wts[2]  = {wt_l0l, wt_l0u};
        for (int lap = 0; lap < 2; ++lap) {
            spmm_csr_kernel<<<SP_BLOCKS, 256, 0, stream>>>(rps[lap], edges[lap], c1, 32, c2);
            spmm_csr_kernel<<<SP_BLOCKS, 256, 0, stream>>>(rps[lap], edges[lap], c2, 32, d1);
            mfma_gemm_kernel<2, false><<<MF_BLOCKS, 256, 0, stream>>>(
                (const ushort*)c2, 32, (const ushort*)d1, 32, wts[lap], 96, nullptr, z);
            spmm_csr_kernel<<<SP_BLOCKS, 256, 0, stream>>>(rps[lap], edges[lap], d1, 32, d2);
            mfma_gemm_kernel<1, false><<<MF_BLOCKS, 256, 0, stream>>>(
                (const ushort*)d2, 32, nullptr, 0, wts[lap] + 64, 96, nullptr, z);
        }
    }

    (void)hipMemsetAsync(stats, 0, 128 * sizeof(double), stream);
    bn_stats_kernel<<<1024, 256, 0, stream>>>(z, stats);
    bn_elu_bf16_kernel<<<2048, 256, 0, stream>>>(z, stats, bn0_g, bn0_b, h0bf);

    // ---------------- layer 1 (H=64 -> H=64) ----------------
    combine_bias_kernel<<<1, 64, 0, stream>>>(l1_bh, l1_bl, l1_bu, cbias);
    mfma_gemm_kernel<2, true><<<MF_BLOCKS, 256, 0, stream>>>(
        h0u, 64, h0u + 32, 64, wt_l1h, 64, cbias, z);

    {
        const int*  rps[2]   = {rpL, rpU};
        const int2* edges[2] = {edgeL, edgeU};
        ushort*     wts[2][2] = {{wt_l1l0, wt_l1l1}, {wt_l1u0, wt_l1u1}};
        for (int lap = 0; lap < 2; ++lap) {
            for (int p = 0; p < 2; ++p) {
                spmm_csr_kernel<<<SP_BLOCKS, 256, 0, stream>>>(
                    rps[lap], edges[lap], h0bf + p * CB, 64, c1);
                spmm_csr_kernel<<<SP_BLOCKS, 256, 0, stream>>>(
                    rps[lap], edges[lap], c1, 32, c2);
                mfma_gemm_kernel<2, false><<<MF_BLOCKS, 256, 0, stream>>>(
                    (const ushort*)c1, 32, (const ushort*)c2, 32, wts[lap][p], 96, nullptr, z);
                spmm_csr_kernel<<<SP_BLOCKS, 256, 0, stream>>>(
                    rps[lap], edges[lap], c2, 32, c1);
                mfma_gemm_kernel<1, false><<<MF_BLOCKS, 256, 0, stream>>>(
                    (const ushort*)c1, 32, nullptr, 0, wts[lap][p] + 64, 96, nullptr, z);
            }
        }
    }

    (void)hipMemsetAsync(stats, 0, 128 * sizeof(double), stream);
    bn_stats_kernel<<<1024, 256, 0, stream>>>(z, stats);
    bn_elu_f32_kernel<<<2048, 256, 0, stream>>>(z, stats, bn1_g, bn1_b);

    // ---------------- pool + MLP ----------------
    pool_kernel<<<G_NUM, 256, 0, stream>>>(z, bidx, gbuf);
    mlp_kernel<<<G_NUM, 64, 0, stream>>>(gbuf, mW1, mb1, mW2, mb2, out);
}

// Round 8
// 2689.518 us; speedup vs baseline: 8.0108x; 1.1649x over previous
//
#include <hip/hip_runtime.h>
#include <hip/hip_bf16.h>
#include <math.h>

#define N_SIMP 400000
#define E_NNZ  2400000
#define FIN    32
#define HDIM   64
#define KAPPA  3
#define G_NUM  512
#define NOUT   8
#define BN_EPS 1e-5

typedef __hip_bfloat16 bf16;
typedef _Float16 f16;
typedef short s8v __attribute__((ext_vector_type(8)));   // 8 bf16 in 4 VGPRs
typedef float f4v __attribute__((ext_vector_type(4)));

__device__ __forceinline__ float elu_f(float x) {
    return x > 0.f ? x : expm1f(x);
}

// ---------------- CSR build ----------------

__global__ void hist2_kernel(const int* __restrict__ eiL, const int* __restrict__ eiU,
                             int* __restrict__ rpL, int* __restrict__ rpU) {
    int idx = blockIdx.x * 256 + threadIdx.x;
    if (idx < E_NNZ) {
        atomicAdd(&rpL[eiL[idx]], 1);
    } else {
        int e = idx - E_NNZ;
        if (e < E_NNZ) atomicAdd(&rpU[eiU[e]], 1);
    }
}

__global__ void scan_block_kernel(int* __restrict__ data, int* __restrict__ bsum, int n) {
    __shared__ int sdata[256];
    int t = threadIdx.x;
    int base = blockIdx.x * 1024 + t * 4;
    int v0 = (base + 0 < n) ? data[base + 0] : 0;
    int v1 = (base + 1 < n) ? data[base + 1] : 0;
    int v2 = (base + 2 < n) ? data[base + 2] : 0;
    int v3 = (base + 3 < n) ? data[base + 3] : 0;
    int tsum = v0 + v1 + v2 + v3;
    sdata[t] = tsum;
    __syncthreads();
    for (int off = 1; off < 256; off <<= 1) {
        int val = (t >= off) ? sdata[t - off] : 0;
        __syncthreads();
        sdata[t] += val;
        __syncthreads();
    }
    if (t == 255) bsum[blockIdx.x] = sdata[255];
    int run = sdata[t] - tsum;
    if (base + 0 < n) { data[base + 0] = run; } run += v0;
    if (base + 1 < n) { data[base + 1] = run; } run += v1;
    if (base + 2 < n) { data[base + 2] = run; } run += v2;
    if (base + 3 < n) { data[base + 3] = run; }
}

__global__ void scan_top_kernel(int* __restrict__ bsum, int nb) {
    if (threadIdx.x == 0 && blockIdx.x == 0) {
        int run = 0;
        for (int i = 0; i < nb; ++i) { int t = bsum[i]; bsum[i] = run; run += t; }
    }
}

__global__ void add_off_kernel(int* __restrict__ rp, const int* __restrict__ bsum) {
    int i = blockIdx.x * 256 + threadIdx.x;
    if (i >= N_SIMP) return;
    rp[i] += bsum[i >> 10];
}

// scatter; rp[r] advances from exclusive-start to end offset
__global__ void scatter2_kernel(const int* __restrict__ eiL, const float* __restrict__ valL,
                                const int* __restrict__ eiU, const float* __restrict__ valU,
                                int* __restrict__ rpL, int* __restrict__ rpU,
                                int2* __restrict__ edgeL, int2* __restrict__ edgeU) {
    int idx = blockIdx.x * 256 + threadIdx.x;
    if (idx < E_NNZ) {
        int r = eiL[idx];
        int pos = atomicAdd(&rpL[r], 1);
        edgeL[pos] = make_int2(eiL[E_NNZ + idx], __float_as_int(valL[idx]));
    } else {
        int e = idx - E_NNZ;
        if (e < E_NNZ) {
            int r = eiU[e];
            int pos = atomicAdd(&rpU[r], 1);
            edgeU[pos] = make_int2(eiU[E_NNZ + e], __float_as_int(valU[e]));
        }
    }
}

// ---------------- small prep kernels ----------------

__global__ void combine_bias_kernel(const float* __restrict__ bh,
                                    const float* __restrict__ bl,
                                    const float* __restrict__ bu,
                                    float* __restrict__ out) {
    int h = threadIdx.x;
    float acc = bh[h];
    for (int k = 0; k < KAPPA; ++k) acc += bl[k * HDIM + h] + bu[k * HDIM + h];
    out[h] = acc;
}

__global__ void f32_to_bf16_kernel(const float* __restrict__ in, bf16* __restrict__ out) {
    int idx = blockIdx.x * 256 + threadIdx.x;
    out[idx] = (bf16)in[idx];
}

// plain transpose: dst[n*Ktot + kk] = bf16(src[kk*64 + n]); src flattened (Ktot, 64)
__global__ void wtrans_kernel(const float* __restrict__ src, ushort* __restrict__ dst, int Ktot) {
    int idx = blockIdx.x * 256 + threadIdx.x;   // grid = 64*Ktot/256
    int n = idx / Ktot;
    int kk = idx - n * Ktot;
    bf16 h = (bf16)src[kk * 64 + n];
    dst[idx] = *(ushort*)&h;
}

// ---------------- SpMM (CSR gather) ----------------
// 32-wide: 2 rows/wave, 8 rows/block (layer 0 chains)
__global__ void spmm32_kernel(const int* __restrict__ rp, const int2* __restrict__ edge,
                              const bf16* __restrict__ src, int src_stride,
                              bf16* __restrict__ dst) {
    int tid = threadIdx.x;
    int lane = tid & 63;
    int wv = tid >> 6;
    int sub = lane >> 5;
    int h = lane & 31;
    int row = blockIdx.x * 8 + wv * 2 + sub;
    int s = (row == 0) ? 0 : rp[row - 1];
    int e = rp[row];
    float a0 = 0.f, a1 = 0.f, a2 = 0.f, a3 = 0.f;
    int j = s;
    for (; j + 3 < e; j += 4) {
        int2 e0 = edge[j];
        int2 e1 = edge[j + 1];
        int2 e2 = edge[j + 2];
        int2 e3 = edge[j + 3];
        float x0 = (float)src[(size_t)e0.x * src_stride + h];
        float x1 = (float)src[(size_t)e1.x * src_stride + h];
        float x2 = (float)src[(size_t)e2.x * src_stride + h];
        float x3 = (float)src[(size_t)e3.x * src_stride + h];
        a0 += __int_as_float(e0.y) * x0;
        a1 += __int_as_float(e1.y) * x1;
        a2 += __int_as_float(e2.y) * x2;
        a3 += __int_as_float(e3.y) * x3;
    }
    for (; j < e; ++j) {
        int2 e0 = edge[j];
        a0 += __int_as_float(e0.y) * (float)src[(size_t)e0.x * src_stride + h];
    }
    dst[(size_t)row * 32 + h] = (bf16)((a0 + a1) + (a2 + a3));
}

// 64-wide: 1 row/wave, 4 rows/block (layer 1 chains); src/dst stride 64
__global__ void spmm64_kernel(const int* __restrict__ rp, const int2* __restrict__ edge,
                              const bf16* __restrict__ src, bf16* __restrict__ dst) {
    int tid = threadIdx.x;
    int h = tid & 63;
    int wv = tid >> 6;
    int row = blockIdx.x * 4 + wv;
    int s = (row == 0) ? 0 : rp[row - 1];
    int e = rp[row];
    float a0 = 0.f, a1 = 0.f, a2 = 0.f, a3 = 0.f;
    int j = s;
    for (; j + 3 < e; j += 4) {
        int2 e0 = edge[j];
        int2 e1 = edge[j + 1];
        int2 e2 = edge[j + 2];
        int2 e3 = edge[j + 3];
        float x0 = (float)src[(size_t)e0.x * 64 + h];
        float x1 = (float)src[(size_t)e1.x * 64 + h];
        float x2 = (float)src[(size_t)e2.x * 64 + h];
        float x3 = (float)src[(size_t)e3.x * 64 + h];
        a0 += __int_as_float(e0.y) * x0;
        a1 += __int_as_float(e1.y) * x1;
        a2 += __int_as_float(e2.y) * x2;
        a3 += __int_as_float(e3.y) * x3;
    }
    for (; j < e; ++j) {
        int2 e0 = edge[j];
        a0 += __int_as_float(e0.y) * (float)src[(size_t)e0.x * 64 + h];
    }
    dst[(size_t)row * 64 + h] = (bf16)((a0 + a1) + (a2 + a3));
}

// ---------------- MFMA GEMM: z[N,64] (fp16) (=bias+ / +=) A[N, NCH*32] @ W -------
// A as up to 4 chunks of 32 bf16 cols (ptr, stride). Wt bf16 [64][Kstride] n-major.
// Block = 4 waves; wave = 16 rows x 64 cols; grid = N/64.

template <int NCH, bool INIT>
__global__ __launch_bounds__(256) void mfma_gemm_kernel(
        const ushort* __restrict__ s0, int st0,
        const ushort* __restrict__ s1, int st1,
        const ushort* __restrict__ s2, int st2,
        const ushort* __restrict__ s3, int st3,
        const ushort* __restrict__ Wt, int Kstride,
        const float* __restrict__ bias,
        f16* __restrict__ z) {
    int tid = threadIdx.x;
    int wv = tid >> 6, lane = tid & 63;
    int quad = lane >> 4, n = lane & 15;
    int rowbase = blockIdx.x * 64 + wv * 16;
    int arow = rowbase + n;  // A-operand row m = lane&15

    f4v acc0 = {0.f, 0.f, 0.f, 0.f};
    f4v acc1 = {0.f, 0.f, 0.f, 0.f};
    f4v acc2 = {0.f, 0.f, 0.f, 0.f};
    f4v acc3 = {0.f, 0.f, 0.f, 0.f};

#pragma unroll
    for (int ch = 0; ch < NCH; ++ch) {
        const ushort* sp = (ch == 0) ? s0 : (ch == 1) ? s1 : (ch == 2) ? s2 : s3;
        int st = (ch == 0) ? st0 : (ch == 1) ? st1 : (ch == 2) ? st2 : st3;
        s8v a = *(const s8v*)(sp + (size_t)arow * st + quad * 8);
        const ushort* wb = Wt + ch * 32 + quad * 8;
        s8v b0 = *(const s8v*)(wb + (size_t)(0 * 16 + n) * Kstride);
        s8v b1 = *(const s8v*)(wb + (size_t)(1 * 16 + n) * Kstride);
        s8v b2 = *(const s8v*)(wb + (size_t)(2 * 16 + n) * Kstride);
        s8v b3 = *(const s8v*)(wb + (size_t)(3 * 16 + n) * Kstride);
        acc0 = __builtin_amdgcn_mfma_f32_16x16x32_bf16(a, b0, acc0, 0, 0, 0);
        acc1 = __builtin_amdgcn_mfma_f32_16x16x32_bf16(a, b1, acc1, 0, 0, 0);
        acc2 = __builtin_amdgcn_mfma_f32_16x16x32_bf16(a, b2, acc2, 0, 0, 0);
        acc3 = __builtin_amdgcn_mfma_f32_16x16x32_bf16(a, b3, acc3, 0, 0, 0);
    }
    // C/D layout: col = lane&15, row = quad*4 + reg
#pragma unroll
    for (int r = 0; r < 4; ++r) {
        int orow = rowbase + quad * 4 + r;
        f16* zp = z + (size_t)orow * 64 + n;
        if (INIT) {
            zp[0]  = (f16)(bias[n]      + acc0[r]);
            zp[16] = (f16)(bias[16 + n] + acc1[r]);
            zp[32] = (f16)(bias[32 + n] + acc2[r]);
            zp[48] = (f16)(bias[48 + n] + acc3[r]);
        } else {
            zp[0]  = (f16)((float)zp[0]  + acc0[r]);
            zp[16] = (f16)((float)zp[16] + acc1[r]);
            zp[32] = (f16)((float)zp[32] + acc2[r]);
            zp[48] = (f16)((float)zp[48] + acc3[r]);
        }
    }
}

// ---------------- BN / pool / MLP ----------------

__global__ void bn_stats_kernel(const f16* __restrict__ z, double* __restrict__ stats) {
    __shared__ double s1[256], s2[256];
    int tid = threadIdx.x;
    const long long total = (long long)N_SIMP * HDIM;
    double sum = 0.0, sq = 0.0;
    for (long long idx = (long long)blockIdx.x * 256 + tid; idx < total;
         idx += (long long)gridDim.x * 256) {
        float v = (float)z[idx];
        sum += v;
        sq += (double)v * v;
    }
    s1[tid] = sum; s2[tid] = sq;
    __syncthreads();
    if (tid < 64) {
        double a = s1[tid] + s1[tid + 64] + s1[tid + 128] + s1[tid + 192];
        double b = s2[tid] + s2[tid + 64] + s2[tid + 128] + s2[tid + 192];
        atomicAdd(&stats[tid], a);
        atomicAdd(&stats[64 + tid], b);
    }
}

// layer-0: h0bf = bf16(elu(bn(z)))
__global__ void bn_elu_bf16_kernel(const f16* __restrict__ z, const double* __restrict__ stats,
                                   const float* __restrict__ gamma, const float* __restrict__ beta,
                                   bf16* __restrict__ out) {
    __shared__ float scale_s[64], shift_s[64];
    int tid = threadIdx.x;
    if (tid < 64) {
        double mean = stats[tid] / (double)N_SIMP;
        double var = stats[64 + tid] / (double)N_SIMP - mean * mean;
        double sc = (double)gamma[tid] / sqrt(var + BN_EPS);
        scale_s[tid] = (float)sc;
        shift_s[tid] = (float)((double)beta[tid] - mean * sc);
    }
    __syncthreads();
    const long long total = (long long)N_SIMP * HDIM;
    for (long long idx = (long long)blockIdx.x * 256 + tid; idx < total;
         idx += (long long)gridDim.x * 256) {
        int h = (int)(idx & 63);
        out[idx] = (bf16)elu_f((float)z[idx] * scale_s[h] + shift_s[h]);
    }
}

// layer-1: z = elu(bn(z)) in place (fp16)
__global__ void bn_elu_f16_kernel(f16* __restrict__ z, const double* __restrict__ stats,
                                  const float* __restrict__ gamma, const float* __restrict__ beta) {
    __shared__ float scale_s[64], shift_s[64];
    int tid = threadIdx.x;
    if (tid < 64) {
        double mean = stats[tid] / (double)N_SIMP;
        double var = stats[64 + tid] / (double)N_SIMP - mean * mean;
        double sc = (double)gamma[tid] / sqrt(var + BN_EPS);
        scale_s[tid] = (float)sc;
        shift_s[tid] = (float)((double)beta[tid] - mean * sc);
    }
    __syncthreads();
    const long long total = (long long)N_SIMP * HDIM;
    for (long long idx = (long long)blockIdx.x * 256 + tid; idx < total;
         idx += (long long)gridDim.x * 256) {
        int h = (int)(idx & 63);
        z[idx] = (f16)elu_f((float)z[idx] * scale_s[h] + shift_s[h]);
    }
}

__global__ void pool_kernel(const f16* __restrict__ hbuf, const int* __restrict__ bidx,
                            float* __restrict__ gbuf) {
    __shared__ float smax[256], ssum[256];
    int g = blockIdx.x;
    int tid = threadIdx.x;
    int lo = 0, hi = N_SIMP;
    while (lo < hi) { int mid = (lo + hi) >> 1; if (bidx[mid] < g) lo = mid + 1; else hi = mid; }
    int start = lo;
    hi = N_SIMP;
    while (lo < hi) { int mid = (lo + hi) >> 1; if (bidx[mid] < g + 1) lo = mid + 1; else hi = mid; }
    int end = lo;
    int h = tid & 63, rep = tid >> 6;
    float mx = -INFINITY, sm = 0.f;
    for (int i = start + rep; i < end; i += 4) {
        float v = (float)hbuf[(size_t)i * HDIM + h];
        mx = fmaxf(mx, v);
        sm += v;
    }
    smax[tid] = mx; ssum[tid] = sm;
    __syncthreads();
    if (tid < 64) {
        float m = fmaxf(fmaxf(smax[tid], smax[tid + 64]), fmaxf(smax[tid + 128], smax[tid + 192]));
        float s = ssum[tid] + ssum[tid + 64] + ssum[tid + 128] + ssum[tid + 192];
        int cnt = end - start;
        float mean = s / fmaxf((float)cnt, 1.f);
        gbuf[g * 128 + tid] = elu_f(m);
        gbuf[g * 128 + 64 + tid] = elu_f(mean);
    }
}

__global__ void mlp_kernel(const float* __restrict__ gbuf, const float* __restrict__ W1,
                           const float* __restrict__ b1, const float* __restrict__ W2,
                           const float* __restrict__ b2, float* __restrict__ out) {
    __shared__ float gs[128];
    __shared__ float hs[64];
    int g = blockIdx.x, tid = threadIdx.x;
    gs[tid] = gbuf[g * 128 + tid];
    gs[64 + tid] = gbuf[g * 128 + 64 + tid];
    __syncthreads();
    float acc = b1[tid];
#pragma unroll
    for (int k = 0; k < 128; ++k) acc += gs[k] * W1[k * 64 + tid];
    hs[tid] = fmaxf(acc, 0.f);
    __syncthreads();
    if (tid < 8) {
        float o = b2[tid];
#pragma unroll
        for (int k = 0; k < 64; ++k) o += hs[k] * W2[k * 8 + tid];
        out[g * 8 + tid] = o;
    }
}

// ---------------- host side ----------------

extern "C" void kernel_launch(void* const* d_in, const int* in_sizes, int n_in,
                              void* d_out, int out_size, void* d_ws, size_t ws_size,
                              hipStream_t stream) {
    const float* x     = (const float*)d_in[0];
    const int*   li    = (const int*)d_in[1];
    const float* lv    = (const float*)d_in[2];
    const int*   ui    = (const int*)d_in[3];
    const float* uv    = (const float*)d_in[4];
    const int*   bidx  = (const int*)d_in[5];
    const float* l0_Wl = (const float*)d_in[6];
    const float* l0_bl = (const float*)d_in[7];
    const float* l0_Wu = (const float*)d_in[8];
    const float* l0_bu = (const float*)d_in[9];
    const float* l0_Wh = (const float*)d_in[10];
    const float* l0_bh = (const float*)d_in[11];
    const float* l1_Wl = (const float*)d_in[12];
    const float* l1_bl = (const float*)d_in[13];
    const float* l1_Wu = (const float*)d_in[14];
    const float* l1_bu = (const float*)d_in[15];
    const float* l1_Wh = (const float*)d_in[16];
    const float* l1_bh = (const float*)d_in[17];
    const float* bn0_g = (const float*)d_in[18];
    const float* bn0_b = (const float*)d_in[19];
    const float* bn1_g = (const float*)d_in[20];
    const float* bn1_b = (const float*)d_in[21];
    const float* mW1   = (const float*)d_in[22];
    const float* mb1   = (const float*)d_in[23];
    const float* mW2   = (const float*)d_in[24];
    const float* mb2   = (const float*)d_in[25];
    float* out = (float*)d_out;

    // ---- workspace layout (total ~246.8 MB <= 256 MiB) ----
    char* base = (char*)d_ws;
    f16*   z     = (f16*)base;                                    //  51,200,000
    bf16*  h0bf  = (bf16*)(base + 51200000ull);                   //  51,200,000
    bf16*  g1    = (bf16*)(base + 102400000ull);                  //  51,200,000
    bf16*  g2    = (bf16*)(base + 153600000ull);                  //  51,200,000
    int2*  edgeL = (int2*)(base + 204800000ull);                  //  19,200,000
    int2*  edgeU = (int2*)(base + 224000000ull);                  //  19,200,000
    int*   rpL   = (int*)(base + 243200000ull);                   //   1,600,032
    int*   rpU   = (int*)(base + 244800032ull);                   //   1,600,032
    int*   bsum  = (int*)(base + 246400064ull);                   //   4 KB
    double* stats = (double*)(base + 246404160ull);               //   1 KB
    float* cbias  = (float*)(base + 246405184ull);                //   256 B
    float* gbuf   = (float*)(base + 246405440ull);                //   262,144
    ushort* wt    = (ushort*)(base + 246667584ull);               //   86,016

    // layer-0 scratch: 4 slots of N*32 bf16 inside g1/g2
    bf16* xbf = g1;
    bf16* cA  = g1 + (size_t)N_SIMP * 32;
    bf16* cB  = g2;
    bf16* cC  = g2 + (size_t)N_SIMP * 32;

    // weight-transpose sub-buffers (ushort elements)
    ushort* wt_l0h = wt;            // 64 x 32
    ushort* wt_l1h = wt + 2048;     // 64 x 64
    ushort* wt_l0l = wt + 6144;     // 64 x 96
    ushort* wt_l0u = wt + 12288;    // 64 x 96
    ushort* wt_l1l = wt + 18432;    // 64 x 192
    ushort* wt_l1u = wt + 30720;    // 64 x 192

    const int SP32_BLOCKS = N_SIMP / 8;    // 50,000
    const int SP64_BLOCKS = N_SIMP / 4;    // 100,000
    const int MF_BLOCKS   = N_SIMP / 64;   // 6,250
    const int EB = (E_NNZ + 255) / 256;
    const int NB1024 = (N_SIMP + 1023) / 1024;
    const int NB256 = (N_SIMP + 255) / 256;

    // ---- prep: weight transposes + x->bf16 ----
    wtrans_kernel<<<8, 256, 0, stream>>>(l0_Wh, wt_l0h, 32);
    wtrans_kernel<<<16, 256, 0, stream>>>(l1_Wh, wt_l1h, 64);
    wtrans_kernel<<<24, 256, 0, stream>>>(l0_Wl, wt_l0l, 96);
    wtrans_kernel<<<24, 256, 0, stream>>>(l0_Wu, wt_l0u, 96);
    wtrans_kernel<<<48, 256, 0, stream>>>(l1_Wl, wt_l1l, 192);
    wtrans_kernel<<<48, 256, 0, stream>>>(l1_Wu, wt_l1u, 192);
    f32_to_bf16_kernel<<<N_SIMP * 32 / 256, 256, 0, stream>>>(x, xbf);

    // ---- CSR builds (both Laplacians, merged dispatches) ----
    (void)hipMemsetAsync(rpL, 0, (N_SIMP + 1) * sizeof(int), stream);
    (void)hipMemsetAsync(rpU, 0, (N_SIMP + 1) * sizeof(int), stream);
    hist2_kernel<<<2 * EB, 256, 0, stream>>>(li, ui, rpL, rpU);
    scan_block_kernel<<<NB1024, 256, 0, stream>>>(rpL, bsum, N_SIMP);
    scan_top_kernel<<<1, 64, 0, stream>>>(bsum, NB1024);
    add_off_kernel<<<NB256, 256, 0, stream>>>(rpL, bsum);
    scan_block_kernel<<<NB1024, 256, 0, stream>>>(rpU, bsum, N_SIMP);
    scan_top_kernel<<<1, 64, 0, stream>>>(bsum, NB1024);
    add_off_kernel<<<NB256, 256, 0, stream>>>(rpU, bsum);
    scatter2_kernel<<<2 * EB, 256, 0, stream>>>(li, lv, ui, uv, rpL, rpU, edgeL, edgeU);

    const ushort* xbfu = (const ushort*)xbf;
    const ushort* h0u  = (const ushort*)h0bf;
    const ushort* g1u  = (const ushort*)g1;
    const ushort* g2u  = (const ushort*)g2;

    // ---------------- layer 0 (F_IN=32 -> H=64), 32-wide chains ----------------
    combine_bias_kernel<<<1, 64, 0, stream>>>(l0_bh, l0_bl, l0_bu, cbias);
    mfma_gemm_kernel<1, true><<<MF_BLOCKS, 256, 0, stream>>>(
        xbfu, 32, nullptr, 0, nullptr, 0, nullptr, 0, wt_l0h, 32, cbias, z);

    // lower chain
    spmm32_kernel<<<SP32_BLOCKS, 256, 0, stream>>>(rpL, edgeL, xbf, 32, cA);
    spmm32_kernel<<<SP32_BLOCKS, 256, 0, stream>>>(rpL, edgeL, cA, 32, cB);
    spmm32_kernel<<<SP32_BLOCKS, 256, 0, stream>>>(rpL, edgeL, cB, 32, cC);
    mfma_gemm_kernel<3, false><<<MF_BLOCKS, 256, 0, stream>>>(
        (const ushort*)cA, 32, (const ushort*)cB, 32, (const ushort*)cC, 32,
        nullptr, 0, wt_l0l, 96, nullptr, z);
    // upper chain
    spmm32_kernel<<<SP32_BLOCKS, 256, 0, stream>>>(rpU, edgeU, xbf, 32, cA);
    spmm32_kernel<<<SP32_BLOCKS, 256, 0, stream>>>(rpU, edgeU, cA, 32, cB);
    spmm32_kernel<<<SP32_BLOCKS, 256, 0, stream>>>(rpU, edgeU, cB, 32, cC);
    mfma_gemm_kernel<3, false><<<MF_BLOCKS, 256, 0, stream>>>(
        (const ushort*)cA, 32, (const ushort*)cB, 32, (const ushort*)cC, 32,
        nullptr, 0, wt_l0u, 96, nullptr, z);

    (void)hipMemsetAsync(stats, 0, 128 * sizeof(double), stream);
    bn_stats_kernel<<<1024, 256, 0, stream>>>(z, stats);
    bn_elu_bf16_kernel<<<2048, 256, 0, stream>>>(z, stats, bn0_g, bn0_b, h0bf);

    // ---------------- layer 1 (H=64 -> H=64), 64-wide chains ----------------
    combine_bias_kernel<<<1, 64, 0, stream>>>(l1_bh, l1_bl, l1_bu, cbias);
    mfma_gemm_kernel<2, true><<<MF_BLOCKS, 256, 0, stream>>>(
        h0u, 64, h0u + 32, 64, nullptr, 0, nullptr, 0, wt_l1h, 64, cbias, z);

    {
        const int*  rps[2]   = {rpL, rpU};
        const int2* edges[2] = {edgeL, edgeU};
        ushort*     wts[2]   = {wt_l1l, wt_l1u};
        for (int lap = 0; lap < 2; ++lap) {
            spmm64_kernel<<<SP64_BLOCKS, 256, 0, stream>>>(rps[lap], edges[lap], h0bf, g1);
            spmm64_kernel<<<SP64_BLOCKS, 256, 0, stream>>>(rps[lap], edges[lap], g1, g2);
            mfma_gemm_kernel<4, false><<<MF_BLOCKS, 256, 0, stream>>>(
                g1u, 64, g1u + 32, 64, g2u, 64, g2u + 32, 64, wts[lap], 192, nullptr, z);
            spmm64_kernel<<<SP64_BLOCKS, 256, 0, stream>>>(rps[lap], edges[lap], g2, g1);
            mfma_gemm_kernel<2, false><<<MF_BLOCKS, 256, 0, stream>>>(
                g1u, 64, g1u + 32, 64, nullptr, 0, nullptr, 0, wts[lap] + 128, 192, nullptr, z);
        }
    }

    (void)hipMemsetAsync(stats, 0, 128 * sizeof(double), stream);
    bn_stats_kernel<<<1024, 256, 0, stream>>>(z, stats);
    bn_elu_f16_kernel<<<2048, 256, 0, stream>>>(z, stats, bn1_g, bn1_b);

    // ---------------- pool + MLP ----------------
    pool_kernel<<<G_NUM, 256, 0, stream>>>(z, bidx, gbuf);
    mlp_kernel<<<G_NUM, 64, 0, stream>>>(gbuf, mW1, mb1, mW2, mb2, out);
}

// Round 9
// 2626.360 us; speedup vs baseline: 8.2034x; 1.0240x over previous
//
#include <hip/hip_runtime.h>
#include <hip/hip_bf16.h>
#include <math.h>

#define N_SIMP 400000
#define E_NNZ  2400000
#define FIN    32
#define HDIM   64
#define KAPPA  3
#define G_NUM  512
#define NOUT   8
#define BN_EPS 1e-5

typedef __hip_bfloat16 bf16;
typedef _Float16 f16;
typedef short s8v __attribute__((ext_vector_type(8)));   // 8 bf16 in 4 VGPRs
typedef float f4v __attribute__((ext_vector_type(4)));

__device__ __forceinline__ float elu_f(float x) {
    return x > 0.f ? x : expm1f(x);
}

// ---------------- CSR build ----------------

__global__ void hist2_kernel(const int* __restrict__ eiL, const int* __restrict__ eiU,
                             int* __restrict__ rpL, int* __restrict__ rpU) {
    int idx = blockIdx.x * 256 + threadIdx.x;
    if (idx < E_NNZ) {
        atomicAdd(&rpL[eiL[idx]], 1);
    } else {
        int e = idx - E_NNZ;
        if (e < E_NNZ) atomicAdd(&rpU[eiU[e]], 1);
    }
}

__global__ void scan_block_kernel(int* __restrict__ data, int* __restrict__ bsum, int n) {
    __shared__ int sdata[256];
    int t = threadIdx.x;
    int base = blockIdx.x * 1024 + t * 4;
    int v0 = (base + 0 < n) ? data[base + 0] : 0;
    int v1 = (base + 1 < n) ? data[base + 1] : 0;
    int v2 = (base + 2 < n) ? data[base + 2] : 0;
    int v3 = (base + 3 < n) ? data[base + 3] : 0;
    int tsum = v0 + v1 + v2 + v3;
    sdata[t] = tsum;
    __syncthreads();
    for (int off = 1; off < 256; off <<= 1) {
        int val = (t >= off) ? sdata[t - off] : 0;
        __syncthreads();
        sdata[t] += val;
        __syncthreads();
    }
    if (t == 255) bsum[blockIdx.x] = sdata[255];
    int run = sdata[t] - tsum;
    if (base + 0 < n) { data[base + 0] = run; } run += v0;
    if (base + 1 < n) { data[base + 1] = run; } run += v1;
    if (base + 2 < n) { data[base + 2] = run; } run += v2;
    if (base + 3 < n) { data[base + 3] = run; }
}

__global__ void scan_top_kernel(int* __restrict__ bsum, int nb) {
    if (threadIdx.x == 0 && blockIdx.x == 0) {
        int run = 0;
        for (int i = 0; i < nb; ++i) { int t = bsum[i]; bsum[i] = run; run += t; }
    }
}

__global__ void add_off_kernel(int* __restrict__ rp, const int* __restrict__ bsum) {
    int i = blockIdx.x * 256 + threadIdx.x;
    if (i >= N_SIMP) return;
    rp[i] += bsum[i >> 10];
}

// scatter; rp[r] advances from exclusive-start to end offset
__global__ void scatter2_kernel(const int* __restrict__ eiL, const float* __restrict__ valL,
                                const int* __restrict__ eiU, const float* __restrict__ valU,
                                int* __restrict__ rpL, int* __restrict__ rpU,
                                int2* __restrict__ edgeL, int2* __restrict__ edgeU) {
    int idx = blockIdx.x * 256 + threadIdx.x;
    if (idx < E_NNZ) {
        int r = eiL[idx];
        int pos = atomicAdd(&rpL[r], 1);
        edgeL[pos] = make_int2(eiL[E_NNZ + idx], __float_as_int(valL[idx]));
    } else {
        int e = idx - E_NNZ;
        if (e < E_NNZ) {
            int r = eiU[e];
            int pos = atomicAdd(&rpU[r], 1);
            edgeU[pos] = make_int2(eiU[E_NNZ + e], __float_as_int(valU[e]));
        }
    }
}

// ---------------- small prep kernels ----------------

__global__ void combine_bias_kernel(const float* __restrict__ bh,
                                    const float* __restrict__ bl,
                                    const float* __restrict__ bu,
                                    float* __restrict__ out) {
    int h = threadIdx.x;
    float acc = bh[h];
    for (int k = 0; k < KAPPA; ++k) acc += bl[k * HDIM + h] + bu[k * HDIM + h];
    out[h] = acc;
}

__global__ void f32_to_bf16_kernel(const float* __restrict__ in, bf16* __restrict__ out) {
    int idx = blockIdx.x * 256 + threadIdx.x;
    out[idx] = (bf16)in[idx];
}

// plain transpose: dst[n*Ktot + kk] = bf16(src[kk*64 + n]); src flattened (Ktot, 64)
__global__ void wtrans_kernel(const float* __restrict__ src, ushort* __restrict__ dst, int Ktot) {
    int idx = blockIdx.x * 256 + threadIdx.x;   // grid = 64*Ktot/256
    int n = idx / Ktot;
    int kk = idx - n * Ktot;
    bf16 h = (bf16)src[kk * 64 + n];
    dst[idx] = *(ushort*)&h;
}

// ---------------- SpMM (CSR gather, batched-prefetch for latency) ----------------
// Strategy: load up to 8 edges of the row in ONE batch (clamped; pad vals zeroed),
// then issue all 8 gathers as one independent batch -> ~2 serial latency windows
// per row instead of ~6. Rows with deg>8 take extra 4-edge batches (14% of rows).

// 32-wide: 2 rows/wave (half-wave each), 8 rows/block
__global__ void spmm32_kernel(const int* __restrict__ rp, const int2* __restrict__ edge,
                              const bf16* __restrict__ src, int src_stride,
                              bf16* __restrict__ dst) {
    int tid = threadIdx.x;
    int lane = tid & 63;
    int wv = tid >> 6;
    int sub = lane >> 5;
    int h = lane & 31;
    int row = blockIdx.x * 8 + wv * 2 + sub;
    int s = (row == 0) ? 0 : rp[row - 1];
    int e = rp[row];
    int deg = e - s;
    float acc = 0.f;
    if (deg > 0) {
        int2 ed[8];
#pragma unroll
        for (int t = 0; t < 8; ++t) {
            int j = s + t;
            ed[t] = edge[(j < e) ? j : (e - 1)];
        }
        float vv[8], xs[8];
#pragma unroll
        for (int t = 0; t < 8; ++t) {
            vv[t] = (t < deg) ? __int_as_float(ed[t].y) : 0.f;
            xs[t] = (float)src[(size_t)ed[t].x * src_stride + h];
        }
        float a0 = 0.f, a1 = 0.f;
#pragma unroll
        for (int t = 0; t < 8; t += 2) {
            a0 += vv[t] * xs[t];
            a1 += vv[t + 1] * xs[t + 1];
        }
        acc = a0 + a1;
        // tail for deg > 8, in 4-edge batches
        for (int j = s + 8; j < e; j += 4) {
            int2 e2[4];
#pragma unroll
            for (int t = 0; t < 4; ++t) {
                int jj = j + t;
                e2[t] = edge[(jj < e) ? jj : (e - 1)];
            }
#pragma unroll
            for (int t = 0; t < 4; ++t) {
                float v = (j + t < e) ? __int_as_float(e2[t].y) : 0.f;
                acc += v * (float)src[(size_t)e2[t].x * src_stride + h];
            }
        }
    }
    dst[(size_t)row * 32 + h] = (bf16)acc;
}

// 64-wide: 1 row/wave, 4 rows/block; src/dst stride 64
__global__ void spmm64_kernel(const int* __restrict__ rp, const int2* __restrict__ edge,
                              const bf16* __restrict__ src, bf16* __restrict__ dst) {
    int tid = threadIdx.x;
    int h = tid & 63;
    int wv = tid >> 6;
    int row = blockIdx.x * 4 + wv;
    int s = (row == 0) ? 0 : rp[row - 1];
    int e = rp[row];
    int deg = e - s;
    float acc = 0.f;
    if (deg > 0) {
        int2 ed[8];
#pragma unroll
        for (int t = 0; t < 8; ++t) {
            int j = s + t;
            ed[t] = edge[(j < e) ? j : (e - 1)];
        }
        float vv[8], xs[8];
#pragma unroll
        for (int t = 0; t < 8; ++t) {
            vv[t] = (t < deg) ? __int_as_float(ed[t].y) : 0.f;
            xs[t] = (float)src[(size_t)ed[t].x * 64 + h];
        }
        float a0 = 0.f, a1 = 0.f;
#pragma unroll
        for (int t = 0; t < 8; t += 2) {
            a0 += vv[t] * xs[t];
            a1 += vv[t + 1] * xs[t + 1];
        }
        acc = a0 + a1;
        for (int j = s + 8; j < e; j += 4) {
            int2 e2[4];
#pragma unroll
            for (int t = 0; t < 4; ++t) {
                int jj = j + t;
                e2[t] = edge[(jj < e) ? jj : (e - 1)];
            }
#pragma unroll
            for (int t = 0; t < 4; ++t) {
                float v = (j + t < e) ? __int_as_float(e2[t].y) : 0.f;
                acc += v * (float)src[(size_t)e2[t].x * 64 + h];
            }
        }
    }
    dst[(size_t)row * 64 + h] = (bf16)acc;
}

// ---------------- MFMA GEMM: z[N,64] (fp16) (=bias+ / +=) A[N, NCH*32] @ W -------
// A as up to 4 chunks of 32 bf16 cols (ptr, stride). Wt bf16 [64][Kstride] n-major.
// Block = 4 waves; wave = 16 rows x 64 cols; grid = N/64.

template <int NCH, bool INIT>
__global__ __launch_bounds__(256) void mfma_gemm_kernel(
        const ushort* __restrict__ s0, int st0,
        const ushort* __restrict__ s1, int st1,
        const ushort* __restrict__ s2, int st2,
        const ushort* __restrict__ s3, int st3,
        const ushort* __restrict__ Wt, int Kstride,
        const float* __restrict__ bias,
        f16* __restrict__ z) {
    int tid = threadIdx.x;
    int wv = tid >> 6, lane = tid & 63;
    int quad = lane >> 4, n = lane & 15;
    int rowbase = blockIdx.x * 64 + wv * 16;
    int arow = rowbase + n;  // A-operand row m = lane&15

    f4v acc0 = {0.f, 0.f, 0.f, 0.f};
    f4v acc1 = {0.f, 0.f, 0.f, 0.f};
    f4v acc2 = {0.f, 0.f, 0.f, 0.f};
    f4v acc3 = {0.f, 0.f, 0.f, 0.f};

#pragma unroll
    for (int ch = 0; ch < NCH; ++ch) {
        const ushort* sp = (ch == 0) ? s0 : (ch == 1) ? s1 : (ch == 2) ? s2 : s3;
        int st = (ch == 0) ? st0 : (ch == 1) ? st1 : (ch == 2) ? st2 : st3;
        s8v a = *(const s8v*)(sp + (size_t)arow * st + quad * 8);
        const ushort* wb = Wt + ch * 32 + quad * 8;
        s8v b0 = *(const s8v*)(wb + (size_t)(0 * 16 + n) * Kstride);
        s8v b1 = *(const s8v*)(wb + (size_t)(1 * 16 + n) * Kstride);
        s8v b2 = *(const s8v*)(wb + (size_t)(2 * 16 + n) * Kstride);
        s8v b3 = *(const s8v*)(wb + (size_t)(3 * 16 + n) * Kstride);
        acc0 = __builtin_amdgcn_mfma_f32_16x16x32_bf16(a, b0, acc0, 0, 0, 0);
        acc1 = __builtin_amdgcn_mfma_f32_16x16x32_bf16(a, b1, acc1, 0, 0, 0);
        acc2 = __builtin_amdgcn_mfma_f32_16x16x32_bf16(a, b2, acc2, 0, 0, 0);
        acc3 = __builtin_amdgcn_mfma_f32_16x16x32_bf16(a, b3, acc3, 0, 0, 0);
    }
    // C/D layout: col = lane&15, row = quad*4 + reg
#pragma unroll
    for (int r = 0; r < 4; ++r) {
        int orow = rowbase + quad * 4 + r;
        f16* zp = z + (size_t)orow * 64 + n;
        if (INIT) {
            zp[0]  = (f16)(bias[n]      + acc0[r]);
            zp[16] = (f16)(bias[16 + n] + acc1[r]);
            zp[32] = (f16)(bias[32 + n] + acc2[r]);
            zp[48] = (f16)(bias[48 + n] + acc3[r]);
        } else {
            zp[0]  = (f16)((float)zp[0]  + acc0[r]);
            zp[16] = (f16)((float)zp[16] + acc1[r]);
            zp[32] = (f16)((float)zp[32] + acc2[r]);
            zp[48] = (f16)((float)zp[48] + acc3[r]);
        }
    }
}

// ---------------- BN / pool / MLP ----------------

__global__ void bn_stats_kernel(const f16* __restrict__ z, double* __restrict__ stats) {
    __shared__ double s1[256], s2[256];
    int tid = threadIdx.x;
    const long long total = (long long)N_SIMP * HDIM;
    double sum = 0.0, sq = 0.0;
    for (long long idx = (long long)blockIdx.x * 256 + tid; idx < total;
         idx += (long long)gridDim.x * 256) {
        float v = (float)z[idx];
        sum += v;
        sq += (double)v * v;
    }
    s1[tid] = sum; s2[tid] = sq;
    __syncthreads();
    if (tid < 64) {
        double a = s1[tid] + s1[tid + 64] + s1[tid + 128] + s1[tid + 192];
        double b = s2[tid] + s2[tid + 64] + s2[tid + 128] + s2[tid + 192];
        atomicAdd(&stats[tid], a);
        atomicAdd(&stats[64 + tid], b);
    }
}

// layer-0: h0bf = bf16(elu(bn(z)))
__global__ void bn_elu_bf16_kernel(const f16* __restrict__ z, const double* __restrict__ stats,
                                   const float* __restrict__ gamma, const float* __restrict__ beta,
                                   bf16* __restrict__ out) {
    __shared__ float scale_s[64], shift_s[64];
    int tid = threadIdx.x;
    if (tid < 64) {
        double mean = stats[tid] / (double)N_SIMP;
        double var = stats[64 + tid] / (double)N_SIMP - mean * mean;
        double sc = (double)gamma[tid] / sqrt(var + BN_EPS);
        scale_s[tid] = (float)sc;
        shift_s[tid] = (float)((double)beta[tid] - mean * sc);
    }
    __syncthreads();
    const long long total = (long long)N_SIMP * HDIM;
    for (long long idx = (long long)blockIdx.x * 256 + tid; idx < total;
         idx += (long long)gridDim.x * 256) {
        int h = (int)(idx & 63);
        out[idx] = (bf16)elu_f((float)z[idx] * scale_s[h] + shift_s[h]);
    }
}

// layer-1: z = elu(bn(z)) in place (fp16)
__global__ void bn_elu_f16_kernel(f16* __restrict__ z, const double* __restrict__ stats,
                                  const float* __restrict__ gamma, const float* __restrict__ beta) {
    __shared__ float scale_s[64], shift_s[64];
    int tid = threadIdx.x;
    if (tid < 64) {
        double mean = stats[tid] / (double)N_SIMP;
        double var = stats[64 + tid] / (double)N_SIMP - mean * mean;
        double sc = (double)gamma[tid] / sqrt(var + BN_EPS);
        scale_s[tid] = (float)sc;
        shift_s[tid] = (float)((double)beta[tid] - mean * sc);
    }
    __syncthreads();
    const long long total = (long long)N_SIMP * HDIM;
    for (long long idx = (long long)blockIdx.x * 256 + tid; idx < total;
         idx += (long long)gridDim.x * 256) {
        int h = (int)(idx & 63);
        z[idx] = (f16)elu_f((float)z[idx] * scale_s[h] + shift_s[h]);
    }
}

__global__ void pool_kernel(const f16* __restrict__ hbuf, const int* __restrict__ bidx,
                            float* __restrict__ gbuf) {
    __shared__ float smax[256], ssum[256];
    int g = blockIdx.x;
    int tid = threadIdx.x;
    int lo = 0, hi = N_SIMP;
    while (lo < hi) { int mid = (lo + hi) >> 1; if (bidx[mid] < g) lo = mid + 1; else hi = mid; }
    int start = lo;
    hi = N_SIMP;
    while (lo < hi) { int mid = (lo + hi) >> 1; if (bidx[mid] < g + 1) lo = mid + 1; else hi = mid; }
    int end = lo;
    int h = tid & 63, rep = tid >> 6;
    float mx = -INFINITY, sm = 0.f;
    for (int i = start + rep; i < end; i += 4) {
        float v = (float)hbuf[(size_t)i * HDIM + h];
        mx = fmaxf(mx, v);
        sm += v;
    }
    smax[tid] = mx; ssum[tid] = sm;
    __syncthreads();
    if (tid < 64) {
        float m = fmaxf(fmaxf(smax[tid], smax[tid + 64]), fmaxf(smax[tid + 128], smax[tid + 192]));
        float s = ssum[tid] + ssum[tid + 64] + ssum[tid + 128] + ssum[tid + 192];
        int cnt = end - start;
        float mean = s / fmaxf((float)cnt, 1.f);
        gbuf[g * 128 + tid] = elu_f(m);
        gbuf[g * 128 + 64 + tid] = elu_f(mean);
    }
}

__global__ void mlp_kernel(const float* __restrict__ gbuf, const float* __restrict__ W1,
                           const float* __restrict__ b1, const float* __restrict__ W2,
                           const float* __restrict__ b2, float* __restrict__ out) {
    __shared__ float gs[128];
    __shared__ float hs[64];
    int g = blockIdx.x, tid = threadIdx.x;
    gs[tid] = gbuf[g * 128 + tid];
    gs[64 + tid] = gbuf[g * 128 + 64 + tid];
    __syncthreads();
    float acc = b1[tid];
#pragma unroll
    for (int k = 0; k < 128; ++k) acc += gs[k] * W1[k * 64 + tid];
    hs[tid] = fmaxf(acc, 0.f);
    __syncthreads();
    if (tid < 8) {
        float o = b2[tid];
#pragma unroll
        for (int k = 0; k < 64; ++k) o += hs[k] * W2[k * 8 + tid];
        out[g * 8 + tid] = o;
    }
}

// ---------------- host side ----------------

extern "C" void kernel_launch(void* const* d_in, const int* in_sizes, int n_in,
                              void* d_out, int out_size, void* d_ws, size_t ws_size,
                              hipStream_t stream) {
    const float* x     = (const float*)d_in[0];
    const int*   li    = (const int*)d_in[1];
    const float* lv    = (const float*)d_in[2];
    const int*   ui    = (const int*)d_in[3];
    const float* uv    = (const float*)d_in[4];
    const int*   bidx  = (const int*)d_in[5];
    const float* l0_Wl = (const float*)d_in[6];
    const float* l0_bl = (const float*)d_in[7];
    const float* l0_Wu = (const float*)d_in[8];
    const float* l0_bu = (const float*)d_in[9];
    const float* l0_Wh = (const float*)d_in[10];
    const float* l0_bh = (const float*)d_in[11];
    const float* l1_Wl = (const float*)d_in[12];
    const float* l1_bl = (const float*)d_in[13];
    const float* l1_Wu = (const float*)d_in[14];
    const float* l1_bu = (const float*)d_in[15];
    const float* l1_Wh = (const float*)d_in[16];
    const float* l1_bh = (const float*)d_in[17];
    const float* bn0_g = (const float*)d_in[18];
    const float* bn0_b = (const float*)d_in[19];
    const float* bn1_g = (const float*)d_in[20];
    const float* bn1_b = (const float*)d_in[21];
    const float* mW1   = (const float*)d_in[22];
    const float* mb1   = (const float*)d_in[23];
    const float* mW2   = (const float*)d_in[24];
    const float* mb2   = (const float*)d_in[25];
    float* out = (float*)d_out;

    // ---- workspace layout (total ~246.8 MB <= 256 MiB) ----
    char* base = (char*)d_ws;
    f16*   z     = (f16*)base;                                    //  51,200,000
    bf16*  h0bf  = (bf16*)(base + 51200000ull);                   //  51,200,000
    bf16*  g1    = (bf16*)(base + 102400000ull);                  //  51,200,000
    bf16*  g2    = (bf16*)(base + 153600000ull);                  //  51,200,000
    int2*  edgeL = (int2*)(base + 204800000ull);                  //  19,200,000
    int2*  edgeU = (int2*)(base + 224000000ull);                  //  19,200,000
    int*   rpL   = (int*)(base + 243200000ull);                   //   1,600,032
    int*   rpU   = (int*)(base + 244800032ull);                   //   1,600,032
    int*   bsum  = (int*)(base + 246400064ull);                   //   4 KB
    double* stats = (double*)(base + 246404160ull);               //   1 KB
    float* cbias  = (float*)(base + 246405184ull);                //   256 B
    float* gbuf   = (float*)(base + 246405440ull);                //   262,144
    ushort* wt    = (ushort*)(base + 246667584ull);               //   86,016

    // layer-0 scratch: 4 slots of N*32 bf16 inside g1/g2
    bf16* xbf = g1;
    bf16* cA  = g1 + (size_t)N_SIMP * 32;
    bf16* cB  = g2;
    bf16* cC  = g2 + (size_t)N_SIMP * 32;

    // weight-transpose sub-buffers (ushort elements)
    ushort* wt_l0h = wt;            // 64 x 32
    ushort* wt_l1h = wt + 2048;     // 64 x 64
    ushort* wt_l0l = wt + 6144;     // 64 x 96
    ushort* wt_l0u = wt + 12288;    // 64 x 96
    ushort* wt_l1l = wt + 18432;    // 64 x 192
    ushort* wt_l1u = wt + 30720;    // 64 x 192

    const int SP32_BLOCKS = N_SIMP / 8;    // 50,000
    const int SP64_BLOCKS = N_SIMP / 4;    // 100,000
    const int MF_BLOCKS   = N_SIMP / 64;   // 6,250
    const int EB = (E_NNZ + 255) / 256;
    const int NB1024 = (N_SIMP + 1023) / 1024;
    const int NB256 = (N_SIMP + 255) / 256;

    // ---- prep: weight transposes + x->bf16 ----
    wtrans_kernel<<<8, 256, 0, stream>>>(l0_Wh, wt_l0h, 32);
    wtrans_kernel<<<16, 256, 0, stream>>>(l1_Wh, wt_l1h, 64);
    wtrans_kernel<<<24, 256, 0, stream>>>(l0_Wl, wt_l0l, 96);
    wtrans_kernel<<<24, 256, 0, stream>>>(l0_Wu, wt_l0u, 96);
    wtrans_kernel<<<48, 256, 0, stream>>>(l1_Wl, wt_l1l, 192);
    wtrans_kernel<<<48, 256, 0, stream>>>(l1_Wu, wt_l1u, 192);
    f32_to_bf16_kernel<<<N_SIMP * 32 / 256, 256, 0, stream>>>(x, xbf);

    // ---- CSR builds (both Laplacians, merged dispatches) ----
    (void)hipMemsetAsync(rpL, 0, (N_SIMP + 1) * sizeof(int), stream);
    (void)hipMemsetAsync(rpU, 0, (N_SIMP + 1) * sizeof(int), stream);
    hist2_kernel<<<2 * EB, 256, 0, stream>>>(li, ui, rpL, rpU);
    scan_block_kernel<<<NB1024, 256, 0, stream>>>(rpL, bsum, N_SIMP);
    scan_top_kernel<<<1, 64, 0, stream>>>(bsum, NB1024);
    add_off_kernel<<<NB256, 256, 0, stream>>>(rpL, bsum);
    scan_block_kernel<<<NB1024, 256, 0, stream>>>(rpU, bsum, N_SIMP);
    scan_top_kernel<<<1, 64, 0, stream>>>(bsum, NB1024);
    add_off_kernel<<<NB256, 256, 0, stream>>>(rpU, bsum);
    scatter2_kernel<<<2 * EB, 256, 0, stream>>>(li, lv, ui, uv, rpL, rpU, edgeL, edgeU);

    const ushort* xbfu = (const ushort*)xbf;
    const ushort* h0u  = (const ushort*)h0bf;
    const ushort* g1u  = (const ushort*)g1;
    const ushort* g2u  = (const ushort*)g2;

    // ---------------- layer 0 (F_IN=32 -> H=64), 32-wide chains ----------------
    combine_bias_kernel<<<1, 64, 0, stream>>>(l0_bh, l0_bl, l0_bu, cbias);
    mfma_gemm_kernel<1, true><<<MF_BLOCKS, 256, 0, stream>>>(
        xbfu, 32, nullptr, 0, nullptr, 0, nullptr, 0, wt_l0h, 32, cbias, z);

    // lower chain
    spmm32_kernel<<<SP32_BLOCKS, 256, 0, stream>>>(rpL, edgeL, xbf, 32, cA);
    spmm32_kernel<<<SP32_BLOCKS, 256, 0, stream>>>(rpL, edgeL, cA, 32, cB);
    spmm32_kernel<<<SP32_BLOCKS, 256, 0, stream>>>(rpL, edgeL, cB, 32, cC);
    mfma_gemm_kernel<3, false><<<MF_BLOCKS, 256, 0, stream>>>(
        (const ushort*)cA, 32, (const ushort*)cB, 32, (const ushort*)cC, 32,
        nullptr, 0, wt_l0l, 96, nullptr, z);
    // upper chain
    spmm32_kernel<<<SP32_BLOCKS, 256, 0, stream>>>(rpU, edgeU, xbf, 32, cA);
    spmm32_kernel<<<SP32_BLOCKS, 256, 0, stream>>>(rpU, edgeU, cA, 32, cB);
    spmm32_kernel<<<SP32_BLOCKS, 256, 0, stream>>>(rpU, edgeU, cB, 32, cC);
    mfma_gemm_kernel<3, false><<<MF_BLOCKS, 256, 0, stream>>>(
        (const ushort*)cA, 32, (const ushort*)cB, 32, (const ushort*)cC, 32,
        nullptr, 0, wt_l0u, 96, nullptr, z);

    (void)hipMemsetAsync(stats, 0, 128 * sizeof(double), stream);
    bn_stats_kernel<<<1024, 256, 0, stream>>>(z, stats);
    bn_elu_bf16_kernel<<<2048, 256, 0, stream>>>(z, stats, bn0_g, bn0_b, h0bf);

    // ---------------- layer 1 (H=64 -> H=64), 64-wide chains ----------------
    combine_bias_kernel<<<1, 64, 0, stream>>>(l1_bh, l1_bl, l1_bu, cbias);
    mfma_gemm_kernel<2, true><<<MF_BLOCKS, 256, 0, stream>>>(
        h0u, 64, h0u + 32, 64, nullptr, 0, nullptr, 0, wt_l1h, 64, cbias, z);

    {
        const int*  rps[2]   = {rpL, rpU};
        const int2* edges[2] = {edgeL, edgeU};
        ushort*     wts[2]   = {wt_l1l, wt_l1u};
        for (int lap = 0; lap < 2; ++lap) {
            spmm64_kernel<<<SP64_BLOCKS, 256, 0, stream>>>(rps[lap], edges[lap], h0bf, g1);
            spmm64_kernel<<<SP64_BLOCKS, 256, 0, stream>>>(rps[lap], edges[lap], g1, g2);
            mfma_gemm_kernel<4, false><<<MF_BLOCKS, 256, 0, stream>>>(
                g1u, 64, g1u + 32, 64, g2u, 64, g2u + 32, 64, wts[lap], 192, nullptr, z);
            spmm64_kernel<<<SP64_BLOCKS, 256, 0, stream>>>(rps[lap], edges[lap], g2, g1);
            mfma_gemm_kernel<2, false><<<MF_BLOCKS, 256, 0, stream>>>(
                g1u, 64, g1u + 32, 64, nullptr, 0, nullptr, 0, wts[lap] + 128, 192, nullptr, z);
        }
    }

    (void)hipMemsetAsync(stats, 0, 128 * sizeof(double), stream);
    bn_stats_kernel<<<1024, 256, 0, stream>>>(z, stats);
    bn_elu_f16_kernel<<<2048, 256, 0, stream>>>(z, stats, bn1_g, bn1_b);

    // ---------------- pool + MLP ----------------
    pool_kernel<<<G_NUM, 256, 0, stream>>>(z, bidx, gbuf);
    mlp_kernel<<<G_NUM, 64, 0, stream>>>(gbuf, mW1, mb1, mW2, mb2, out);
}

// Round 10
// 1946.758 us; speedup vs baseline: 11.0672x; 1.3491x over previous
//
#include <hip/hip_runtime.h>
#include <hip/hip_bf16.h>
#include <math.h>

#define N_SIMP 400000
#define E_NNZ  2400000
#define FIN    32
#define HDIM   64
#define KAPPA  3
#define G_NUM  512
#define NOUT   8
#define BN_EPS 1e-5

typedef __hip_bfloat16 bf16;
typedef _Float16 f16;
typedef short s8v __attribute__((ext_vector_type(8)));   // 8 bf16 in 4 VGPRs
typedef float f4v __attribute__((ext_vector_type(4)));

__device__ __forceinline__ float elu_f(float x) {
    return x > 0.f ? x : expm1f(x);
}
__device__ __forceinline__ float bf2f(ushort u) {
    return __uint_as_float(((unsigned int)u) << 16);
}
__device__ __forceinline__ ushort f2bf(float f) {
    bf16 h = (bf16)f;
    return *(ushort*)&h;
}

// ---------------- CSR build ----------------

__global__ void hist2_kernel(const int* __restrict__ eiL, const int* __restrict__ eiU,
                             int* __restrict__ rpL, int* __restrict__ rpU) {
    int idx = blockIdx.x * 256 + threadIdx.x;
    if (idx < E_NNZ) {
        atomicAdd(&rpL[eiL[idx]], 1);
    } else {
        int e = idx - E_NNZ;
        if (e < E_NNZ) atomicAdd(&rpU[eiU[e]], 1);
    }
}

__global__ void scan_block_kernel(int* __restrict__ data, int* __restrict__ bsum, int n) {
    __shared__ int sdata[256];
    int t = threadIdx.x;
    int base = blockIdx.x * 1024 + t * 4;
    int v0 = (base + 0 < n) ? data[base + 0] : 0;
    int v1 = (base + 1 < n) ? data[base + 1] : 0;
    int v2 = (base + 2 < n) ? data[base + 2] : 0;
    int v3 = (base + 3 < n) ? data[base + 3] : 0;
    int tsum = v0 + v1 + v2 + v3;
    sdata[t] = tsum;
    __syncthreads();
    for (int off = 1; off < 256; off <<= 1) {
        int val = (t >= off) ? sdata[t - off] : 0;
        __syncthreads();
        sdata[t] += val;
        __syncthreads();
    }
    if (t == 255) bsum[blockIdx.x] = sdata[255];
    int run = sdata[t] - tsum;
    if (base + 0 < n) { data[base + 0] = run; } run += v0;
    if (base + 1 < n) { data[base + 1] = run; } run += v1;
    if (base + 2 < n) { data[base + 2] = run; } run += v2;
    if (base + 3 < n) { data[base + 3] = run; }
}

__global__ void scan_top_kernel(int* __restrict__ bsum, int nb) {
    if (threadIdx.x == 0 && blockIdx.x == 0) {
        int run = 0;
        for (int i = 0; i < nb; ++i) { int t = bsum[i]; bsum[i] = run; run += t; }
    }
}

__global__ void add_off_kernel(int* __restrict__ rp, const int* __restrict__ bsum) {
    int i = blockIdx.x * 256 + threadIdx.x;
    if (i >= N_SIMP) return;
    rp[i] += bsum[i >> 10];
}

// scatter; rp[r] advances from exclusive-start to end offset
__global__ void scatter2_kernel(const int* __restrict__ eiL, const float* __restrict__ valL,
                                const int* __restrict__ eiU, const float* __restrict__ valU,
                                int* __restrict__ rpL, int* __restrict__ rpU,
                                int2* __restrict__ edgeL, int2* __restrict__ edgeU) {
    int idx = blockIdx.x * 256 + threadIdx.x;
    if (idx < E_NNZ) {
        int r = eiL[idx];
        int pos = atomicAdd(&rpL[r], 1);
        edgeL[pos] = make_int2(eiL[E_NNZ + idx], __float_as_int(valL[idx]));
    } else {
        int e = idx - E_NNZ;
        if (e < E_NNZ) {
            int r = eiU[e];
            int pos = atomicAdd(&rpU[r], 1);
            edgeU[pos] = make_int2(eiU[E_NNZ + e], __float_as_int(valU[e]));
        }
    }
}

// ---------------- small prep kernels ----------------

__global__ void combine_bias_kernel(const float* __restrict__ bh,
                                    const float* __restrict__ bl,
                                    const float* __restrict__ bu,
                                    float* __restrict__ out) {
    int h = threadIdx.x;
    float acc = bh[h];
    for (int k = 0; k < KAPPA; ++k) acc += bl[k * HDIM + h] + bu[k * HDIM + h];
    out[h] = acc;
}

__global__ void f32_to_bf16_kernel(const float* __restrict__ in, bf16* __restrict__ out) {
    int idx = blockIdx.x * 256 + threadIdx.x;
    out[idx] = (bf16)in[idx];
}

// plain transpose: dst[n*Ktot + kk] = bf16(src[kk*64 + n]); src flattened (Ktot, 64)
__global__ void wtrans_kernel(const float* __restrict__ src, ushort* __restrict__ dst, int Ktot) {
    int idx = blockIdx.x * 256 + threadIdx.x;   // grid = 64*Ktot/256
    int n = idx / Ktot;
    int kk = idx - n * Ktot;
    bf16 h = (bf16)src[kk * 64 + n];
    dst[idx] = *(ushort*)&h;
}

// ---------------- SpMM (CSR gather; high per-wave concurrency) ----------------
// Each lane covers 4 channels (ushort4). 32-wide: 8 rows/wave; 64-wide: 4 rows/wave.
// Up to 8-edge batch prefetched per row -> 32-64 independent gathers in flight/wave.

// 32-wide: 8 lanes/row, 8 rows/wave, 32 rows/block
__global__ void spmm32_kernel(const int* __restrict__ rp, const int2* __restrict__ edge,
                              const bf16* __restrict__ srcb, int src_stride,
                              bf16* __restrict__ dstb) {
    const ushort* src = (const ushort*)srcb;
    ushort* dst = (ushort*)dstb;
    int tid = threadIdx.x;
    int lane = tid & 63;
    int wv = tid >> 6;
    int grp = lane >> 3;      // 0..7: row within wave
    int li = lane & 7;        // lane within row: channels li*4 .. li*4+3
    int row = blockIdx.x * 32 + wv * 8 + grp;
    int s = (row == 0) ? 0 : rp[row - 1];
    int e = rp[row];
    int deg = e - s;
    float a0 = 0.f, a1 = 0.f, a2 = 0.f, a3 = 0.f;
    if (deg > 0) {
        int2 ed[8];
#pragma unroll
        for (int t = 0; t < 8; ++t) {
            int j = s + t;
            ed[t] = edge[(j < e) ? j : (e - 1)];
        }
        ushort4 xs[8];
#pragma unroll
        for (int t = 0; t < 8; ++t)
            xs[t] = *(const ushort4*)(src + (size_t)ed[t].x * src_stride + li * 4);
#pragma unroll
        for (int t = 0; t < 8; ++t) {
            float v = (t < deg) ? __int_as_float(ed[t].y) : 0.f;
            a0 += v * bf2f(xs[t].x);
            a1 += v * bf2f(xs[t].y);
            a2 += v * bf2f(xs[t].z);
            a3 += v * bf2f(xs[t].w);
        }
        for (int j = s + 8; j < e; j += 4) {
            int2 e2[4];
#pragma unroll
            for (int t = 0; t < 4; ++t) {
                int jj = j + t;
                e2[t] = edge[(jj < e) ? jj : (e - 1)];
            }
            ushort4 x2[4];
#pragma unroll
            for (int t = 0; t < 4; ++t)
                x2[t] = *(const ushort4*)(src + (size_t)e2[t].x * src_stride + li * 4);
#pragma unroll
            for (int t = 0; t < 4; ++t) {
                float v = (j + t < e) ? __int_as_float(e2[t].y) : 0.f;
                a0 += v * bf2f(x2[t].x);
                a1 += v * bf2f(x2[t].y);
                a2 += v * bf2f(x2[t].z);
                a3 += v * bf2f(x2[t].w);
            }
        }
    }
    ushort4 w;
    w.x = f2bf(a0); w.y = f2bf(a1); w.z = f2bf(a2); w.w = f2bf(a3);
    *(ushort4*)(dst + (size_t)row * 32 + li * 4) = w;
}

// 64-wide: 16 lanes/row, 4 rows/wave, 16 rows/block; stride 64
__global__ void spmm64_kernel(const int* __restrict__ rp, const int2* __restrict__ edge,
                              const bf16* __restrict__ srcb, bf16* __restrict__ dstb) {
    const ushort* src = (const ushort*)srcb;
    ushort* dst = (ushort*)dstb;
    int tid = threadIdx.x;
    int lane = tid & 63;
    int wv = tid >> 6;
    int grp = lane >> 4;      // 0..3: row within wave
    int li = lane & 15;       // channels li*4 .. li*4+3
    int row = blockIdx.x * 16 + wv * 4 + grp;
    int s = (row == 0) ? 0 : rp[row - 1];
    int e = rp[row];
    int deg = e - s;
    float a0 = 0.f, a1 = 0.f, a2 = 0.f, a3 = 0.f;
    if (deg > 0) {
        int2 ed[8];
#pragma unroll
        for (int t = 0; t < 8; ++t) {
            int j = s + t;
            ed[t] = edge[(j < e) ? j : (e - 1)];
        }
        ushort4 xs[8];
#pragma unroll
        for (int t = 0; t < 8; ++t)
            xs[t] = *(const ushort4*)(src + (size_t)ed[t].x * 64 + li * 4);
#pragma unroll
        for (int t = 0; t < 8; ++t) {
            float v = (t < deg) ? __int_as_float(ed[t].y) : 0.f;
            a0 += v * bf2f(xs[t].x);
            a1 += v * bf2f(xs[t].y);
            a2 += v * bf2f(xs[t].z);
            a3 += v * bf2f(xs[t].w);
        }
        for (int j = s + 8; j < e; j += 4) {
            int2 e2[4];
#pragma unroll
            for (int t = 0; t < 4; ++t) {
                int jj = j + t;
                e2[t] = edge[(jj < e) ? jj : (e - 1)];
            }
            ushort4 x2[4];
#pragma unroll
            for (int t = 0; t < 4; ++t)
                x2[t] = *(const ushort4*)(src + (size_t)e2[t].x * 64 + li * 4);
#pragma unroll
            for (int t = 0; t < 4; ++t) {
                float v = (j + t < e) ? __int_as_float(e2[t].y) : 0.f;
                a0 += v * bf2f(x2[t].x);
                a1 += v * bf2f(x2[t].y);
                a2 += v * bf2f(x2[t].z);
                a3 += v * bf2f(x2[t].w);
            }
        }
    }
    ushort4 w;
    w.x = f2bf(a0); w.y = f2bf(a1); w.z = f2bf(a2); w.w = f2bf(a3);
    *(ushort4*)(dst + (size_t)row * 64 + li * 4) = w;
}

// ---------------- MFMA GEMM: z[N,64] (fp16) (=bias+ / +=) A[N, NCH*32] @ W -------
// A as up to 4 chunks of 32 bf16 cols (ptr, stride). Wt bf16 [64][Kstride] n-major.
// Block = 4 waves; wave = 16 rows x 64 cols; grid = N/64.

template <int NCH, bool INIT>
__global__ __launch_bounds__(256) void mfma_gemm_kernel(
        const ushort* __restrict__ s0, int st0,
        const ushort* __restrict__ s1, int st1,
        const ushort* __restrict__ s2, int st2,
        const ushort* __restrict__ s3, int st3,
        const ushort* __restrict__ Wt, int Kstride,
        const float* __restrict__ bias,
        f16* __restrict__ z) {
    int tid = threadIdx.x;
    int wv = tid >> 6, lane = tid & 63;
    int quad = lane >> 4, n = lane & 15;
    int rowbase = blockIdx.x * 64 + wv * 16;
    int arow = rowbase + n;  // A-operand row m = lane&15

    f4v acc0 = {0.f, 0.f, 0.f, 0.f};
    f4v acc1 = {0.f, 0.f, 0.f, 0.f};
    f4v acc2 = {0.f, 0.f, 0.f, 0.f};
    f4v acc3 = {0.f, 0.f, 0.f, 0.f};

#pragma unroll
    for (int ch = 0; ch < NCH; ++ch) {
        const ushort* sp = (ch == 0) ? s0 : (ch == 1) ? s1 : (ch == 2) ? s2 : s3;
        int st = (ch == 0) ? st0 : (ch == 1) ? st1 : (ch == 2) ? st2 : st3;
        s8v a = *(const s8v*)(sp + (size_t)arow * st + quad * 8);
        const ushort* wb = Wt + ch * 32 + quad * 8;
        s8v b0 = *(const s8v*)(wb + (size_t)(0 * 16 + n) * Kstride);
        s8v b1 = *(const s8v*)(wb + (size_t)(1 * 16 + n) * Kstride);
        s8v b2 = *(const s8v*)(wb + (size_t)(2 * 16 + n) * Kstride);
        s8v b3 = *(const s8v*)(wb + (size_t)(3 * 16 + n) * Kstride);
        acc0 = __builtin_amdgcn_mfma_f32_16x16x32_bf16(a, b0, acc0, 0, 0, 0);
        acc1 = __builtin_amdgcn_mfma_f32_16x16x32_bf16(a, b1, acc1, 0, 0, 0);
        acc2 = __builtin_amdgcn_mfma_f32_16x16x32_bf16(a, b2, acc2, 0, 0, 0);
        acc3 = __builtin_amdgcn_mfma_f32_16x16x32_bf16(a, b3, acc3, 0, 0, 0);
    }
    // C/D layout: col = lane&15, row = quad*4 + reg
#pragma unroll
    for (int r = 0; r < 4; ++r) {
        int orow = rowbase + quad * 4 + r;
        f16* zp = z + (size_t)orow * 64 + n;
        if (INIT) {
            zp[0]  = (f16)(bias[n]      + acc0[r]);
            zp[16] = (f16)(bias[16 + n] + acc1[r]);
            zp[32] = (f16)(bias[32 + n] + acc2[r]);
            zp[48] = (f16)(bias[48 + n] + acc3[r]);
        } else {
            zp[0]  = (f16)((float)zp[0]  + acc0[r]);
            zp[16] = (f16)((float)zp[16] + acc1[r]);
            zp[32] = (f16)((float)zp[32] + acc2[r]);
            zp[48] = (f16)((float)zp[48] + acc3[r]);
        }
    }
}

// ---------------- BN / pool / MLP ----------------

__global__ void bn_stats_kernel(const f16* __restrict__ z, double* __restrict__ stats) {
    __shared__ double s1[256], s2[256];
    int tid = threadIdx.x;
    const long long total = (long long)N_SIMP * HDIM;
    double sum = 0.0, sq = 0.0;
    for (long long idx = (long long)blockIdx.x * 256 + tid; idx < total;
         idx += (long long)gridDim.x * 256) {
        float v = (float)z[idx];
        sum += v;
        sq += (double)v * v;
    }
    s1[tid] = sum; s2[tid] = sq;
    __syncthreads();
    if (tid < 64) {
        double a = s1[tid] + s1[tid + 64] + s1[tid + 128] + s1[tid + 192];
        double b = s2[tid] + s2[tid + 64] + s2[tid + 128] + s2[tid + 192];
        atomicAdd(&stats[tid], a);
        atomicAdd(&stats[64 + tid], b);
    }
}

// layer-0: h0bf = bf16(elu(bn(z)))
__global__ void bn_elu_bf16_kernel(const f16* __restrict__ z, const double* __restrict__ stats,
                                   const float* __restrict__ gamma, const float* __restrict__ beta,
                                   bf16* __restrict__ out) {
    __shared__ float scale_s[64], shift_s[64];
    int tid = threadIdx.x;
    if (tid < 64) {
        double mean = stats[tid] / (double)N_SIMP;
        double var = stats[64 + tid] / (double)N_SIMP - mean * mean;
        double sc = (double)gamma[tid] / sqrt(var + BN_EPS);
        scale_s[tid] = (float)sc;
        shift_s[tid] = (float)((double)beta[tid] - mean * sc);
    }
    __syncthreads();
    const long long total = (long long)N_SIMP * HDIM;
    for (long long idx = (long long)blockIdx.x * 256 + tid; idx < total;
         idx += (long long)gridDim.x * 256) {
        int h = (int)(idx & 63);
        out[idx] = (bf16)elu_f((float)z[idx] * scale_s[h] + shift_s[h]);
    }
}

// layer-1: z = elu(bn(z)) in place (fp16)
__global__ void bn_elu_f16_kernel(f16* __restrict__ z, const double* __restrict__ stats,
                                  const float* __restrict__ gamma, const float* __restrict__ beta) {
    __shared__ float scale_s[64], shift_s[64];
    int tid = threadIdx.x;
    if (tid < 64) {
        double mean = stats[tid] / (double)N_SIMP;
        double var = stats[64 + tid] / (double)N_SIMP - mean * mean;
        double sc = (double)gamma[tid] / sqrt(var + BN_EPS);
        scale_s[tid] = (float)sc;
        shift_s[tid] = (float)((double)beta[tid] - mean * sc);
    }
    __syncthreads();
    const long long total = (long long)N_SIMP * HDIM;
    for (long long idx = (long long)blockIdx.x * 256 + tid; idx < total;
         idx += (long long)gridDim.x * 256) {
        int h = (int)(idx & 63);
        z[idx] = (f16)elu_f((float)z[idx] * scale_s[h] + shift_s[h]);
    }
}

__global__ void pool_kernel(const f16* __restrict__ hbuf, const int* __restrict__ bidx,
                            float* __restrict__ gbuf) {
    __shared__ float smax[256], ssum[256];
    int g = blockIdx.x;
    int tid = threadIdx.x;
    int lo = 0, hi = N_SIMP;
    while (lo < hi) { int mid = (lo + hi) >> 1; if (bidx[mid] < g) lo = mid + 1; else hi = mid; }
    int start = lo;
    hi = N_SIMP;
    while (lo < hi) { int mid = (lo + hi) >> 1; if (bidx[mid] < g + 1) lo = mid + 1; else hi = mid; }
    int end = lo;
    int h = tid & 63, rep = tid >> 6;
    float mx = -INFINITY, sm = 0.f;
    for (int i = start + rep; i < end; i += 4) {
        float v = (float)hbuf[(size_t)i * HDIM + h];
        mx = fmaxf(mx, v);
        sm += v;
    }
    smax[tid] = mx; ssum[tid] = sm;
    __syncthreads();
    if (tid < 64) {
        float m = fmaxf(fmaxf(smax[tid], smax[tid + 64]), fmaxf(smax[tid + 128], smax[tid + 192]));
        float s = ssum[tid] + ssum[tid + 64] + ssum[tid + 128] + ssum[tid + 192];
        int cnt = end - start;
        float mean = s / fmaxf((float)cnt, 1.f);
        gbuf[g * 128 + tid] = elu_f(m);
        gbuf[g * 128 + 64 + tid] = elu_f(mean);
    }
}

__global__ void mlp_kernel(const float* __restrict__ gbuf, const float* __restrict__ W1,
                           const float* __restrict__ b1, const float* __restrict__ W2,
                           const float* __restrict__ b2, float* __restrict__ out) {
    __shared__ float gs[128];
    __shared__ float hs[64];
    int g = blockIdx.x, tid = threadIdx.x;
    gs[tid] = gbuf[g * 128 + tid];
    gs[64 + tid] = gbuf[g * 128 + 64 + tid];
    __syncthreads();
    float acc = b1[tid];
#pragma unroll
    for (int k = 0; k < 128; ++k) acc += gs[k] * W1[k * 64 + tid];
    hs[tid] = fmaxf(acc, 0.f);
    __syncthreads();
    if (tid < 8) {
        float o = b2[tid];
#pragma unroll
        for (int k = 0; k < 64; ++k) o += hs[k] * W2[k * 8 + tid];
        out[g * 8 + tid] = o;
    }
}

// ---------------- host side ----------------

extern "C" void kernel_launch(void* const* d_in, const int* in_sizes, int n_in,
                              void* d_out, int out_size, void* d_ws, size_t ws_size,
                              hipStream_t stream) {
    const float* x     = (const float*)d_in[0];
    const int*   li    = (const int*)d_in[1];
    const float* lv    = (const float*)d_in[2];
    const int*   ui    = (const int*)d_in[3];
    const float* uv    = (const float*)d_in[4];
    const int*   bidx  = (const int*)d_in[5];
    const float* l0_Wl = (const float*)d_in[6];
    const float* l0_bl = (const float*)d_in[7];
    const float* l0_Wu = (const float*)d_in[8];
    const float* l0_bu = (const float*)d_in[9];
    const float* l0_Wh = (const float*)d_in[10];
    const float* l0_bh = (const float*)d_in[11];
    const float* l1_Wl = (const float*)d_in[12];
    const float* l1_bl = (const float*)d_in[13];
    const float* l1_Wu = (const float*)d_in[14];
    const float* l1_bu = (const float*)d_in[15];
    const float* l1_Wh = (const float*)d_in[16];
    const float* l1_bh = (const float*)d_in[17];
    const float* bn0_g = (const float*)d_in[18];
    const float* bn0_b = (const float*)d_in[19];
    const float* bn1_g = (const float*)d_in[20];
    const float* bn1_b = (const float*)d_in[21];
    const float* mW1   = (const float*)d_in[22];
    const float* mb1   = (const float*)d_in[23];
    const float* mW2   = (const float*)d_in[24];
    const float* mb2   = (const float*)d_in[25];
    float* out = (float*)d_out;

    // ---- workspace layout (total ~246.8 MB <= 256 MiB) ----
    char* base = (char*)d_ws;
    f16*   z     = (f16*)base;                                    //  51,200,000
    bf16*  h0bf  = (bf16*)(base + 51200000ull);                   //  51,200,000
    bf16*  g1    = (bf16*)(base + 102400000ull);                  //  51,200,000
    bf16*  g2    = (bf16*)(base + 153600000ull);                  //  51,200,000
    int2*  edgeL = (int2*)(base + 204800000ull);                  //  19,200,000
    int2*  edgeU = (int2*)(base + 224000000ull);                  //  19,200,000
    int*   rpL   = (int*)(base + 243200000ull);                   //   1,600,032
    int*   rpU   = (int*)(base + 244800032ull);                   //   1,600,032
    int*   bsum  = (int*)(base + 246400064ull);                   //   4 KB
    double* stats = (double*)(base + 246404160ull);               //   1 KB
    float* cbias  = (float*)(base + 246405184ull);                //   256 B
    float* gbuf   = (float*)(base + 246405440ull);                //   262,144
    ushort* wt    = (ushort*)(base + 246667584ull);               //   86,016

    // layer-0 scratch: 4 slots of N*32 bf16 inside g1/g2
    bf16* xbf = g1;
    bf16* cA  = g1 + (size_t)N_SIMP * 32;
    bf16* cB  = g2;
    bf16* cC  = g2 + (size_t)N_SIMP * 32;

    // weight-transpose sub-buffers (ushort elements)
    ushort* wt_l0h = wt;            // 64 x 32
    ushort* wt_l1h = wt + 2048;     // 64 x 64
    ushort* wt_l0l = wt + 6144;     // 64 x 96
    ushort* wt_l0u = wt + 12288;    // 64 x 96
    ushort* wt_l1l = wt + 18432;    // 64 x 192
    ushort* wt_l1u = wt + 30720;    // 64 x 192

    const int SP32_BLOCKS = N_SIMP / 32;   // 12,500
    const int SP64_BLOCKS = N_SIMP / 16;   // 25,000
    const int MF_BLOCKS   = N_SIMP / 64;   // 6,250
    const int EB = (E_NNZ + 255) / 256;
    const int NB1024 = (N_SIMP + 1023) / 1024;
    const int NB256 = (N_SIMP + 255) / 256;

    // ---- prep: weight transposes + x->bf16 ----
    wtrans_kernel<<<8, 256, 0, stream>>>(l0_Wh, wt_l0h, 32);
    wtrans_kernel<<<16, 256, 0, stream>>>(l1_Wh, wt_l1h, 64);
    wtrans_kernel<<<24, 256, 0, stream>>>(l0_Wl, wt_l0l, 96);
    wtrans_kernel<<<24, 256, 0, stream>>>(l0_Wu, wt_l0u, 96);
    wtrans_kernel<<<48, 256, 0, stream>>>(l1_Wl, wt_l1l, 192);
    wtrans_kernel<<<48, 256, 0, stream>>>(l1_Wu, wt_l1u, 192);
    f32_to_bf16_kernel<<<N_SIMP * 32 / 256, 256, 0, stream>>>(x, xbf);

    // ---- CSR builds (both Laplacians, merged dispatches) ----
    (void)hipMemsetAsync(rpL, 0, (N_SIMP + 1) * sizeof(int), stream);
    (void)hipMemsetAsync(rpU, 0, (N_SIMP + 1) * sizeof(int), stream);
    hist2_kernel<<<2 * EB, 256, 0, stream>>>(li, ui, rpL, rpU);
    scan_block_kernel<<<NB1024, 256, 0, stream>>>(rpL, bsum, N_SIMP);
    scan_top_kernel<<<1, 64, 0, stream>>>(bsum, NB1024);
    add_off_kernel<<<NB256, 256, 0, stream>>>(rpL, bsum);
    scan_block_kernel<<<NB1024, 256, 0, stream>>>(rpU, bsum, N_SIMP);
    scan_top_kernel<<<1, 64, 0, stream>>>(bsum, NB1024);
    add_off_kernel<<<NB256, 256, 0, stream>>>(rpU, bsum);
    scatter2_kernel<<<2 * EB, 256, 0, stream>>>(li, lv, ui, uv, rpL, rpU, edgeL, edgeU);

    const ushort* xbfu = (const ushort*)xbf;
    const ushort* h0u  = (const ushort*)h0bf;
    const ushort* g1u  = (const ushort*)g1;
    const ushort* g2u  = (const ushort*)g2;

    // ---------------- layer 0 (F_IN=32 -> H=64), 32-wide chains ----------------
    combine_bias_kernel<<<1, 64, 0, stream>>>(l0_bh, l0_bl, l0_bu, cbias);
    mfma_gemm_kernel<1, true><<<MF_BLOCKS, 256, 0, stream>>>(
        xbfu, 32, nullptr, 0, nullptr, 0, nullptr, 0, wt_l0h, 32, cbias, z);

    // lower chain
    spmm32_kernel<<<SP32_BLOCKS, 256, 0, stream>>>(rpL, edgeL, xbf, 32, cA);
    spmm32_kernel<<<SP32_BLOCKS, 256, 0, stream>>>(rpL, edgeL, cA, 32, cB);
    spmm32_kernel<<<SP32_BLOCKS, 256, 0, stream>>>(rpL, edgeL, cB, 32, cC);
    mfma_gemm_kernel<3, false><<<MF_BLOCKS, 256, 0, stream>>>(
        (const ushort*)cA, 32, (const ushort*)cB, 32, (const ushort*)cC, 32,
        nullptr, 0, wt_l0l, 96, nullptr, z);
    // upper chain
    spmm32_kernel<<<SP32_BLOCKS, 256, 0, stream>>>(rpU, edgeU, xbf, 32, cA);
    spmm32_kernel<<<SP32_BLOCKS, 256, 0, stream>>>(rpU, edgeU, cA, 32, cB);
    spmm32_kernel<<<SP32_BLOCKS, 256, 0, stream>>>(rpU, edgeU, cB, 32, cC);
    mfma_gemm_kernel<3, false><<<MF_BLOCKS, 256, 0, stream>>>(
        (const ushort*)cA, 32, (const ushort*)cB, 32, (const ushort*)cC, 32,
        nullptr, 0, wt_l0u, 96, nullptr, z);

    (void)hipMemsetAsync(stats, 0, 128 * sizeof(double), stream);
    bn_stats_kernel<<<1024, 256, 0, stream>>>(z, stats);
    bn_elu_bf16_kernel<<<2048, 256, 0, stream>>>(z, stats, bn0_g, bn0_b, h0bf);

    // ---------------- layer 1 (H=64 -> H=64), 64-wide chains ----------------
    combine_bias_kernel<<<1, 64, 0, stream>>>(l1_bh, l1_bl, l1_bu, cbias);
    mfma_gemm_kernel<2, true><<<MF_BLOCKS, 256, 0, stream>>>(
        h0u, 64, h0u + 32, 64, nullptr, 0, nullptr, 0, wt_l1h, 64, cbias, z);

    {
        const int*  rps[2]   = {rpL, rpU};
        const int2* edges[2] = {edgeL, edgeU};
        ushort*     wts[2]   = {wt_l1l, wt_l1u};
        for (int lap = 0; lap < 2; ++lap) {
            spmm64_kernel<<<SP64_BLOCKS, 256, 0, stream>>>(rps[lap], edges[lap], h0bf, g1);
            spmm64_kernel<<<SP64_BLOCKS, 256, 0, stream>>>(rps[lap], edges[lap], g1, g2);
            mfma_gemm_kernel<4, false><<<MF_BLOCKS, 256, 0, stream>>>(
                g1u, 64, g1u + 32, 64, g2u, 64, g2u + 32, 64, wts[lap], 192, nullptr, z);
            spmm64_kernel<<<SP64_BLOCKS, 256, 0, stream>>>(rps[lap], edges[lap], g2, g1);
            mfma_gemm_kernel<2, false><<<MF_BLOCKS, 256, 0, stream>>>(
                g1u, 64, g1u + 32, 64, nullptr, 0, nullptr, 0, wts[lap] + 128, 192, nullptr, z);
        }
    }

    (void)hipMemsetAsync(stats, 0, 128 * sizeof(double), stream);
    bn_stats_kernel<<<1024, 256, 0, stream>>>(z, stats);
    bn_elu_f16_kernel<<<2048, 256, 0, stream>>>(z, stats, bn1_g, bn1_b);

    // ---------------- pool + MLP ----------------
    pool_kernel<<<G_NUM, 256, 0, stream>>>(z, bidx, gbuf);
    mlp_kernel<<<G_NUM, 64, 0, stream>>>(gbuf, mW1, mb1, mW2, mb2, out);
}

// Round 11
// 1884.620 us; speedup vs baseline: 11.4321x; 1.0330x over previous
//
#include <hip/hip_runtime.h>
#include <hip/hip_bf16.h>
#include <math.h>

#define N_SIMP 400000
#define E_NNZ  2400000
#define FIN    32
#define HDIM   64
#define KAPPA  3
#define G_NUM  512
#define NOUT   8
#define BN_EPS 1e-5

typedef __hip_bfloat16 bf16;
typedef _Float16 f16;
typedef short s8v __attribute__((ext_vector_type(8)));    // 8 bf16 in 4 VGPRs
typedef ushort u8v __attribute__((ext_vector_type(8)));   // 8 bf16 raw
typedef float f4v __attribute__((ext_vector_type(4)));

__device__ __forceinline__ float elu_f(float x) {
    return x > 0.f ? x : expm1f(x);
}
__device__ __forceinline__ float bf2f(ushort u) {
    return __uint_as_float(((unsigned int)u) << 16);
}
__device__ __forceinline__ ushort f2bf(float f) {
    bf16 h = (bf16)f;
    return *(ushort*)&h;
}

// ---------------- CSR build ----------------

__global__ void hist2_kernel(const int* __restrict__ eiL, const int* __restrict__ eiU,
                             int* __restrict__ rpL, int* __restrict__ rpU) {
    int idx = blockIdx.x * 256 + threadIdx.x;
    if (idx < E_NNZ) {
        atomicAdd(&rpL[eiL[idx]], 1);
    } else {
        int e = idx - E_NNZ;
        if (e < E_NNZ) atomicAdd(&rpU[eiU[e]], 1);
    }
}

__global__ void scan_block_kernel(int* __restrict__ data, int* __restrict__ bsum, int n) {
    __shared__ int sdata[256];
    int t = threadIdx.x;
    int base = blockIdx.x * 1024 + t * 4;
    int v0 = (base + 0 < n) ? data[base + 0] : 0;
    int v1 = (base + 1 < n) ? data[base + 1] : 0;
    int v2 = (base + 2 < n) ? data[base + 2] : 0;
    int v3 = (base + 3 < n) ? data[base + 3] : 0;
    int tsum = v0 + v1 + v2 + v3;
    sdata[t] = tsum;
    __syncthreads();
    for (int off = 1; off < 256; off <<= 1) {
        int val = (t >= off) ? sdata[t - off] : 0;
        __syncthreads();
        sdata[t] += val;
        __syncthreads();
    }
    if (t == 255) bsum[blockIdx.x] = sdata[255];
    int run = sdata[t] - tsum;
    if (base + 0 < n) { data[base + 0] = run; } run += v0;
    if (base + 1 < n) { data[base + 1] = run; } run += v1;
    if (base + 2 < n) { data[base + 2] = run; } run += v2;
    if (base + 3 < n) { data[base + 3] = run; }
}

__global__ void scan_top_kernel(int* __restrict__ bsum, int nb) {
    if (threadIdx.x == 0 && blockIdx.x == 0) {
        int run = 0;
        for (int i = 0; i < nb; ++i) { int t = bsum[i]; bsum[i] = run; run += t; }
    }
}

__global__ void add_off_kernel(int* __restrict__ rp, const int* __restrict__ bsum) {
    int i = blockIdx.x * 256 + threadIdx.x;
    if (i >= N_SIMP) return;
    rp[i] += bsum[i >> 10];
}

// scatter; rp[r] advances from exclusive-start to end offset
__global__ void scatter2_kernel(const int* __restrict__ eiL, const float* __restrict__ valL,
                                const int* __restrict__ eiU, const float* __restrict__ valU,
                                int* __restrict__ rpL, int* __restrict__ rpU,
                                int2* __restrict__ edgeL, int2* __restrict__ edgeU) {
    int idx = blockIdx.x * 256 + threadIdx.x;
    if (idx < E_NNZ) {
        int r = eiL[idx];
        int pos = atomicAdd(&rpL[r], 1);
        edgeL[pos] = make_int2(eiL[E_NNZ + idx], __float_as_int(valL[idx]));
    } else {
        int e = idx - E_NNZ;
        if (e < E_NNZ) {
            int r = eiU[e];
            int pos = atomicAdd(&rpU[r], 1);
            edgeU[pos] = make_int2(eiU[E_NNZ + e], __float_as_int(valU[e]));
        }
    }
}

// ---------------- small prep kernels ----------------

__global__ void combine_bias_kernel(const float* __restrict__ bh,
                                    const float* __restrict__ bl,
                                    const float* __restrict__ bu,
                                    float* __restrict__ out) {
    int h = threadIdx.x;
    float acc = bh[h];
    for (int k = 0; k < KAPPA; ++k) acc += bl[k * HDIM + h] + bu[k * HDIM + h];
    out[h] = acc;
}

__global__ void f32_to_bf16_kernel(const float* __restrict__ in, bf16* __restrict__ out) {
    int idx = blockIdx.x * 256 + threadIdx.x;
    out[idx] = (bf16)in[idx];
}

// all 6 weight transposes in one dispatch; wt layout fixed (offsets in ushorts)
__global__ void wtrans_all_kernel(const float* __restrict__ s0, const float* __restrict__ s1,
                                  const float* __restrict__ s2, const float* __restrict__ s3,
                                  const float* __restrict__ s4, const float* __restrict__ s5,
                                  ushort* __restrict__ wt) {
    int idx = blockIdx.x * 256 + threadIdx.x;   // 0..43007
    const float* src; int Ktot, off;
    if (idx < 2048)       { src = s0; Ktot = 32;  off = 0; }
    else if (idx < 6144)  { src = s1; Ktot = 64;  off = 2048; }
    else if (idx < 12288) { src = s2; Ktot = 96;  off = 6144; }
    else if (idx < 18432) { src = s3; Ktot = 96;  off = 12288; }
    else if (idx < 30720) { src = s4; Ktot = 192; off = 18432; }
    else                  { src = s5; Ktot = 192; off = 30720; }
    int rel = idx - off;
    int n = rel / Ktot, kk = rel - n * Ktot;
    wt[idx] = f2bf(src[kk * 64 + n]);
}

// ---------------- SpMM (CSR gather; max per-wave concurrency, 16B lanes) --------

// 32-wide: 4 lanes/row (8 ch each), 16 rows/wave, 64 rows/block
__global__ void spmm32_kernel(const int* __restrict__ rp, const int2* __restrict__ edge,
                              const bf16* __restrict__ srcb, int src_stride,
                              bf16* __restrict__ dstb) {
    const ushort* src = (const ushort*)srcb;
    ushort* dst = (ushort*)dstb;
    int tid = threadIdx.x;
    int lane = tid & 63;
    int wv = tid >> 6;
    int grp = lane >> 2;      // 0..15: row within wave
    int li = lane & 3;        // channels li*8 .. li*8+7
    int row = blockIdx.x * 64 + wv * 16 + grp;
    int s = (row == 0) ? 0 : rp[row - 1];
    int e = rp[row];
    int deg = e - s;
    float a[8] = {0.f, 0.f, 0.f, 0.f, 0.f, 0.f, 0.f, 0.f};
    if (deg > 0) {
        int2 ed[8];
#pragma unroll
        for (int t = 0; t < 8; ++t) {
            int j = s + t;
            ed[t] = edge[(j < e) ? j : (e - 1)];
        }
        u8v xs[8];
#pragma unroll
        for (int t = 0; t < 8; ++t)
            xs[t] = *(const u8v*)(src + (size_t)ed[t].x * src_stride + li * 8);
#pragma unroll
        for (int t = 0; t < 8; ++t) {
            float v = (t < deg) ? __int_as_float(ed[t].y) : 0.f;
#pragma unroll
            for (int c = 0; c < 8; ++c) a[c] += v * bf2f(xs[t][c]);
        }
        for (int j = s + 8; j < e; j += 4) {
            int2 e2[4];
#pragma unroll
            for (int t = 0; t < 4; ++t) {
                int jj = j + t;
                e2[t] = edge[(jj < e) ? jj : (e - 1)];
            }
            u8v x2[4];
#pragma unroll
            for (int t = 0; t < 4; ++t)
                x2[t] = *(const u8v*)(src + (size_t)e2[t].x * src_stride + li * 8);
#pragma unroll
            for (int t = 0; t < 4; ++t) {
                float v = (j + t < e) ? __int_as_float(e2[t].y) : 0.f;
#pragma unroll
                for (int c = 0; c < 8; ++c) a[c] += v * bf2f(x2[t][c]);
            }
        }
    }
    u8v w;
#pragma unroll
    for (int c = 0; c < 8; ++c) w[c] = f2bf(a[c]);
    *(u8v*)(dst + (size_t)row * 32 + li * 8) = w;
}

// 64-wide: 8 lanes/row (8 ch each), 8 rows/wave, 32 rows/block; stride 64
__global__ void spmm64_kernel(const int* __restrict__ rp, const int2* __restrict__ edge,
                              const bf16* __restrict__ srcb, bf16* __restrict__ dstb) {
    const ushort* src = (const ushort*)srcb;
    ushort* dst = (ushort*)dstb;
    int tid = threadIdx.x;
    int lane = tid & 63;
    int wv = tid >> 6;
    int grp = lane >> 3;      // 0..7: row within wave
    int li = lane & 7;        // channels li*8 .. li*8+7
    int row = blockIdx.x * 32 + wv * 8 + grp;
    int s = (row == 0) ? 0 : rp[row - 1];
    int e = rp[row];
    int deg = e - s;
    float a[8] = {0.f, 0.f, 0.f, 0.f, 0.f, 0.f, 0.f, 0.f};
    if (deg > 0) {
        int2 ed[8];
#pragma unroll
        for (int t = 0; t < 8; ++t) {
            int j = s + t;
            ed[t] = edge[(j < e) ? j : (e - 1)];
        }
        u8v xs[8];
#pragma unroll
        for (int t = 0; t < 8; ++t)
            xs[t] = *(const u8v*)(src + (size_t)ed[t].x * 64 + li * 8);
#pragma unroll
        for (int t = 0; t < 8; ++t) {
            float v = (t < deg) ? __int_as_float(ed[t].y) : 0.f;
#pragma unroll
            for (int c = 0; c < 8; ++c) a[c] += v * bf2f(xs[t][c]);
        }
        for (int j = s + 8; j < e; j += 4) {
            int2 e2[4];
#pragma unroll
            for (int t = 0; t < 4; ++t) {
                int jj = j + t;
                e2[t] = edge[(jj < e) ? jj : (e - 1)];
            }
            u8v x2[4];
#pragma unroll
            for (int t = 0; t < 4; ++t)
                x2[t] = *(const u8v*)(src + (size_t)e2[t].x * 64 + li * 8);
#pragma unroll
            for (int t = 0; t < 4; ++t) {
                float v = (j + t < e) ? __int_as_float(e2[t].y) : 0.f;
#pragma unroll
                for (int c = 0; c < 8; ++c) a[c] += v * bf2f(x2[t][c]);
            }
        }
    }
    u8v w;
#pragma unroll
    for (int c = 0; c < 8; ++c) w[c] = f2bf(a[c]);
    *(u8v*)(dst + (size_t)row * 64 + li * 8) = w;
}

// ---------------- MFMA GEMM: z[N,64] (fp16) (=bias+ / +=) A[N, NCH*32] @ W -------

template <int NCH, bool INIT>
__global__ __launch_bounds__(256) void mfma_gemm_kernel(
        const ushort* __restrict__ s0, int st0,
        const ushort* __restrict__ s1, int st1,
        const ushort* __restrict__ s2, int st2,
        const ushort* __restrict__ s3, int st3,
        const ushort* __restrict__ Wt, int Kstride,
        const float* __restrict__ bias,
        f16* __restrict__ z) {
    int tid = threadIdx.x;
    int wv = tid >> 6, lane = tid & 63;
    int quad = lane >> 4, n = lane & 15;
    int rowbase = blockIdx.x * 64 + wv * 16;
    int arow = rowbase + n;  // A-operand row m = lane&15

    f4v acc0 = {0.f, 0.f, 0.f, 0.f};
    f4v acc1 = {0.f, 0.f, 0.f, 0.f};
    f4v acc2 = {0.f, 0.f, 0.f, 0.f};
    f4v acc3 = {0.f, 0.f, 0.f, 0.f};

#pragma unroll
    for (int ch = 0; ch < NCH; ++ch) {
        const ushort* sp = (ch == 0) ? s0 : (ch == 1) ? s1 : (ch == 2) ? s2 : s3;
        int st = (ch == 0) ? st0 : (ch == 1) ? st1 : (ch == 2) ? st2 : st3;
        s8v a = *(const s8v*)(sp + (size_t)arow * st + quad * 8);
        const ushort* wb = Wt + ch * 32 + quad * 8;
        s8v b0 = *(const s8v*)(wb + (size_t)(0 * 16 + n) * Kstride);
        s8v b1 = *(const s8v*)(wb + (size_t)(1 * 16 + n) * Kstride);
        s8v b2 = *(const s8v*)(wb + (size_t)(2 * 16 + n) * Kstride);
        s8v b3 = *(const s8v*)(wb + (size_t)(3 * 16 + n) * Kstride);
        acc0 = __builtin_amdgcn_mfma_f32_16x16x32_bf16(a, b0, acc0, 0, 0, 0);
        acc1 = __builtin_amdgcn_mfma_f32_16x16x32_bf16(a, b1, acc1, 0, 0, 0);
        acc2 = __builtin_amdgcn_mfma_f32_16x16x32_bf16(a, b2, acc2, 0, 0, 0);
        acc3 = __builtin_amdgcn_mfma_f32_16x16x32_bf16(a, b3, acc3, 0, 0, 0);
    }
    // C/D layout: col = lane&15, row = quad*4 + reg
#pragma unroll
    for (int r = 0; r < 4; ++r) {
        int orow = rowbase + quad * 4 + r;
        f16* zp = z + (size_t)orow * 64 + n;
        if (INIT) {
            zp[0]  = (f16)(bias[n]      + acc0[r]);
            zp[16] = (f16)(bias[16 + n] + acc1[r]);
            zp[32] = (f16)(bias[32 + n] + acc2[r]);
            zp[48] = (f16)(bias[48 + n] + acc3[r]);
        } else {
            zp[0]  = (f16)((float)zp[0]  + acc0[r]);
            zp[16] = (f16)((float)zp[16] + acc1[r]);
            zp[32] = (f16)((float)zp[32] + acc2[r]);
            zp[48] = (f16)((float)zp[48] + acc3[r]);
        }
    }
}

// ---------------- BN / pool / MLP ----------------

__global__ void bn_stats_kernel(const f16* __restrict__ z, double* __restrict__ stats) {
    __shared__ double s1[256], s2[256];
    int tid = threadIdx.x;
    const long long total = (long long)N_SIMP * HDIM;
    double sum = 0.0, sq = 0.0;
    for (long long idx = (long long)blockIdx.x * 256 + tid; idx < total;
         idx += (long long)gridDim.x * 256) {
        float v = (float)z[idx];
        sum += v;
        sq += (double)v * v;
    }
    s1[tid] = sum; s2[tid] = sq;
    __syncthreads();
    if (tid < 64) {
        double a = s1[tid] + s1[tid + 64] + s1[tid + 128] + s1[tid + 192];
        double b = s2[tid] + s2[tid + 64] + s2[tid + 128] + s2[tid + 192];
        atomicAdd(&stats[tid], a);
        atomicAdd(&stats[64 + tid], b);
    }
}

// layer-0: h0bf = bf16(elu(bn(z)))
__global__ void bn_elu_bf16_kernel(const f16* __restrict__ z, const double* __restrict__ stats,
                                   const float* __restrict__ gamma, const float* __restrict__ beta,
                                   bf16* __restrict__ out) {
    __shared__ float scale_s[64], shift_s[64];
    int tid = threadIdx.x;
    if (tid < 64) {
        double mean = stats[tid] / (double)N_SIMP;
        double var = stats[64 + tid] / (double)N_SIMP - mean * mean;
        double sc = (double)gamma[tid] / sqrt(var + BN_EPS);
        scale_s[tid] = (float)sc;
        shift_s[tid] = (float)((double)beta[tid] - mean * sc);
    }
    __syncthreads();
    const long long total = (long long)N_SIMP * HDIM;
    for (long long idx = (long long)blockIdx.x * 256 + tid; idx < total;
         idx += (long long)gridDim.x * 256) {
        int h = (int)(idx & 63);
        out[idx] = (bf16)elu_f((float)z[idx] * scale_s[h] + shift_s[h]);
    }
}

// layer-1: z = elu(bn(z)) in place (fp16)
__global__ void bn_elu_f16_kernel(f16* __restrict__ z, const double* __restrict__ stats,
                                  const float* __restrict__ gamma, const float* __restrict__ beta) {
    __shared__ float scale_s[64], shift_s[64];
    int tid = threadIdx.x;
    if (tid < 64) {
        double mean = stats[tid] / (double)N_SIMP;
        double var = stats[64 + tid] / (double)N_SIMP - mean * mean;
        double sc = (double)gamma[tid] / sqrt(var + BN_EPS);
        scale_s[tid] = (float)sc;
        shift_s[tid] = (float)((double)beta[tid] - mean * sc);
    }
    __syncthreads();
    const long long total = (long long)N_SIMP * HDIM;
    for (long long idx = (long long)blockIdx.x * 256 + tid; idx < total;
         idx += (long long)gridDim.x * 256) {
        int h = (int)(idx & 63);
        z[idx] = (f16)elu_f((float)z[idx] * scale_s[h] + shift_s[h]);
    }
}

__global__ void pool_kernel(const f16* __restrict__ hbuf, const int* __restrict__ bidx,
                            float* __restrict__ gbuf) {
    __shared__ float smax[256], ssum[256];
    int g = blockIdx.x;
    int tid = threadIdx.x;
    int lo = 0, hi = N_SIMP;
    while (lo < hi) { int mid = (lo + hi) >> 1; if (bidx[mid] < g) lo = mid + 1; else hi = mid; }
    int start = lo;
    hi = N_SIMP;
    while (lo < hi) { int mid = (lo + hi) >> 1; if (bidx[mid] < g + 1) lo = mid + 1; else hi = mid; }
    int end = lo;
    int h = tid & 63, rep = tid >> 6;
    float mx = -INFINITY, sm = 0.f;
    for (int i = start + rep; i < end; i += 4) {
        float v = (float)hbuf[(size_t)i * HDIM + h];
        mx = fmaxf(mx, v);
        sm += v;
    }
    smax[tid] = mx; ssum[tid] = sm;
    __syncthreads();
    if (tid < 64) {
        float m = fmaxf(fmaxf(smax[tid], smax[tid + 64]), fmaxf(smax[tid + 128], smax[tid + 192]));
        float s = ssum[tid] + ssum[tid + 64] + ssum[tid + 128] + ssum[tid + 192];
        int cnt = end - start;
        float mean = s / fmaxf((float)cnt, 1.f);
        gbuf[g * 128 + tid] = elu_f(m);
        gbuf[g * 128 + 64 + tid] = elu_f(mean);
    }
}

__global__ void mlp_kernel(const float* __restrict__ gbuf, const float* __restrict__ W1,
                           const float* __restrict__ b1, const float* __restrict__ W2,
                           const float* __restrict__ b2, float* __restrict__ out) {
    __shared__ float gs[128];
    __shared__ float hs[64];
    int g = blockIdx.x, tid = threadIdx.x;
    gs[tid] = gbuf[g * 128 + tid];
    gs[64 + tid] = gbuf[g * 128 + 64 + tid];
    __syncthreads();
    float acc = b1[tid];
#pragma unroll
    for (int k = 0; k < 128; ++k) acc += gs[k] * W1[k * 64 + tid];
    hs[tid] = fmaxf(acc, 0.f);
    __syncthreads();
    if (tid < 8) {
        float o = b2[tid];
#pragma unroll
        for (int k = 0; k < 64; ++k) o += hs[k] * W2[k * 8 + tid];
        out[g * 8 + tid] = o;
    }
}

// ---------------- host side ----------------

extern "C" void kernel_launch(void* const* d_in, const int* in_sizes, int n_in,
                              void* d_out, int out_size, void* d_ws, size_t ws_size,
                              hipStream_t stream) {
    const float* x     = (const float*)d_in[0];
    const int*   li    = (const int*)d_in[1];
    const float* lv    = (const float*)d_in[2];
    const int*   ui    = (const int*)d_in[3];
    const float* uv    = (const float*)d_in[4];
    const int*   bidx  = (const int*)d_in[5];
    const float* l0_Wl = (const float*)d_in[6];
    const float* l0_bl = (const float*)d_in[7];
    const float* l0_Wu = (const float*)d_in[8];
    const float* l0_bu = (const float*)d_in[9];
    const float* l0_Wh = (const float*)d_in[10];
    const float* l0_bh = (const float*)d_in[11];
    const float* l1_Wl = (const float*)d_in[12];
    const float* l1_bl = (const float*)d_in[13];
    const float* l1_Wu = (const float*)d_in[14];
    const float* l1_bu = (const float*)d_in[15];
    const float* l1_Wh = (const float*)d_in[16];
    const float* l1_bh = (const float*)d_in[17];
    const float* bn0_g = (const float*)d_in[18];
    const float* bn0_b = (const float*)d_in[19];
    const float* bn1_g = (const float*)d_in[20];
    const float* bn1_b = (const float*)d_in[21];
    const float* mW1   = (const float*)d_in[22];
    const float* mb1   = (const float*)d_in[23];
    const float* mW2   = (const float*)d_in[24];
    const float* mb2   = (const float*)d_in[25];
    float* out = (float*)d_out;

    // ---- workspace layout (total ~246.8 MB <= 256 MiB) ----
    char* base = (char*)d_ws;
    f16*   z     = (f16*)base;                                    //  51,200,000
    bf16*  h0bf  = (bf16*)(base + 51200000ull);                   //  51,200,000
    bf16*  g1    = (bf16*)(base + 102400000ull);                  //  51,200,000
    bf16*  g2    = (bf16*)(base + 153600000ull);                  //  51,200,000
    int2*  edgeL = (int2*)(base + 204800000ull);                  //  19,200,000
    int2*  edgeU = (int2*)(base + 224000000ull);                  //  19,200,000
    int*   rpL   = (int*)(base + 243200000ull);                   //   1,600,032
    int*   rpU   = (int*)(base + 244800032ull);                   //   1,600,032
    int*   bsum  = (int*)(base + 246400064ull);                   //   4 KB
    double* stats = (double*)(base + 246404160ull);               //   1 KB
    float* cbias  = (float*)(base + 246405184ull);                //   256 B
    float* gbuf   = (float*)(base + 246405440ull);                //   262,144
    ushort* wt    = (ushort*)(base + 246667584ull);               //   86,016

    // layer-0 scratch: 4 slots of N*32 bf16 inside g1/g2
    bf16* xbf = g1;
    bf16* cA  = g1 + (size_t)N_SIMP * 32;
    bf16* cB  = g2;
    bf16* cC  = g2 + (size_t)N_SIMP * 32;

    // weight-transpose sub-buffers (ushort elements; offsets match wtrans_all_kernel)
    ushort* wt_l0h = wt;            // 64 x 32
    ushort* wt_l1h = wt + 2048;     // 64 x 64
    ushort* wt_l0l = wt + 6144;     // 64 x 96
    ushort* wt_l0u = wt + 12288;    // 64 x 96
    ushort* wt_l1l = wt + 18432;    // 64 x 192
    ushort* wt_l1u = wt + 30720;    // 64 x 192

    const int SP32_BLOCKS = N_SIMP / 64;   // 6,250
    const int SP64_BLOCKS = N_SIMP / 32;   // 12,500
    const int MF_BLOCKS   = N_SIMP / 64;   // 6,250
    const int EB = (E_NNZ + 255) / 256;
    const int NB1024 = (N_SIMP + 1023) / 1024;
    const int NB256 = (N_SIMP + 255) / 256;

    // ---- prep: weight transposes (one dispatch) + x->bf16 ----
    wtrans_all_kernel<<<168, 256, 0, stream>>>(l0_Wh, l1_Wh, l0_Wl, l0_Wu, l1_Wl, l1_Wu, wt);
    f32_to_bf16_kernel<<<N_SIMP * 32 / 256, 256, 0, stream>>>(x, xbf);

    // ---- CSR builds (both Laplacians, merged dispatches; rpL/rpU contiguous) ----
    (void)hipMemsetAsync(rpL, 0, 3200064ull, stream);
    hist2_kernel<<<2 * EB, 256, 0, stream>>>(li, ui, rpL, rpU);
    scan_block_kernel<<<NB1024, 256, 0, stream>>>(rpL, bsum, N_SIMP);
    scan_top_kernel<<<1, 64, 0, stream>>>(bsum, NB1024);
    add_off_kernel<<<NB256, 256, 0, stream>>>(rpL, bsum);
    scan_block_kernel<<<NB1024, 256, 0, stream>>>(rpU, bsum, N_SIMP);
    scan_top_kernel<<<1, 64, 0, stream>>>(bsum, NB1024);
    add_off_kernel<<<NB256, 256, 0, stream>>>(rpU, bsum);
    scatter2_kernel<<<2 * EB, 256, 0, stream>>>(li, lv, ui, uv, rpL, rpU, edgeL, edgeU);

    const ushort* xbfu = (const ushort*)xbf;
    const ushort* h0u  = (const ushort*)h0bf;
    const ushort* g1u  = (const ushort*)g1;
    const ushort* g2u  = (const ushort*)g2;

    // ---------------- layer 0 (F_IN=32 -> H=64), 32-wide chains ----------------
    combine_bias_kernel<<<1, 64, 0, stream>>>(l0_bh, l0_bl, l0_bu, cbias);
    mfma_gemm_kernel<1, true><<<MF_BLOCKS, 256, 0, stream>>>(
        xbfu, 32, nullptr, 0, nullptr, 0, nullptr, 0, wt_l0h, 32, cbias, z);

    // lower chain
    spmm32_kernel<<<SP32_BLOCKS, 256, 0, stream>>>(rpL, edgeL, xbf, 32, cA);
    spmm32_kernel<<<SP32_BLOCKS, 256, 0, stream>>>(rpL, edgeL, cA, 32, cB);
    spmm32_kernel<<<SP32_BLOCKS, 256, 0, stream>>>(rpL, edgeL, cB, 32, cC);
    mfma_gemm_kernel<3, false><<<MF_BLOCKS, 256, 0, stream>>>(
        (const ushort*)cA, 32, (const ushort*)cB, 32, (const ushort*)cC, 32,
        nullptr, 0, wt_l0l, 96, nullptr, z);
    // upper chain
    spmm32_kernel<<<SP32_BLOCKS, 256, 0, stream>>>(rpU, edgeU, xbf, 32, cA);
    spmm32_kernel<<<SP32_BLOCKS, 256, 0, stream>>>(rpU, edgeU, cA, 32, cB);
    spmm32_kernel<<<SP32_BLOCKS, 256, 0, stream>>>(rpU, edgeU, cB, 32, cC);
    mfma_gemm_kernel<3, false><<<MF_BLOCKS, 256, 0, stream>>>(
        (const ushort*)cA, 32, (const ushort*)cB, 32, (const ushort*)cC, 32,
        nullptr, 0, wt_l0u, 96, nullptr, z);

    (void)hipMemsetAsync(stats, 0, 128 * sizeof(double), stream);
    bn_stats_kernel<<<1024, 256, 0, stream>>>(z, stats);
    bn_elu_bf16_kernel<<<2048, 256, 0, stream>>>(z, stats, bn0_g, bn0_b, h0bf);

    // ---------------- layer 1 (H=64 -> H=64), 64-wide chains ----------------
    combine_bias_kernel<<<1, 64, 0, stream>>>(l1_bh, l1_bl, l1_bu, cbias);
    mfma_gemm_kernel<2, true><<<MF_BLOCKS, 256, 0, stream>>>(
        h0u, 64, h0u + 32, 64, nullptr, 0, nullptr, 0, wt_l1h, 64, cbias, z);

    {
        const int*  rps[2]   = {rpL, rpU};
        const int2* edges[2] = {edgeL, edgeU};
        ushort*     wts[2]   = {wt_l1l, wt_l1u};
        for (int lap = 0; lap < 2; ++lap) {
            spmm64_kernel<<<SP64_BLOCKS, 256, 0, stream>>>(rps[lap], edges[lap], h0bf, g1);
            spmm64_kernel<<<SP64_BLOCKS, 256, 0, stream>>>(rps[lap], edges[lap], g1, g2);
            mfma_gemm_kernel<4, false><<<MF_BLOCKS, 256, 0, stream>>>(
                g1u, 64, g1u + 32, 64, g2u, 64, g2u + 32, 64, wts[lap], 192, nullptr, z);
            spmm64_kernel<<<SP64_BLOCKS, 256, 0, stream>>>(rps[lap], edges[lap], g2, g1);
            mfma_gemm_kernel<2, false><<<MF_BLOCKS, 256, 0, stream>>>(
                g1u, 64, g1u + 32, 64, nullptr, 0, nullptr, 0, wts[lap] + 128, 192, nullptr, z);
        }
    }

    (void)hipMemsetAsync(stats, 0, 128 * sizeof(double), stream);
    bn_stats_kernel<<<1024, 256, 0, stream>>>(z, stats);
    bn_elu_f16_kernel<<<2048, 256, 0, stream>>>(z, stats, bn1_g, bn1_b);

    // ---------------- pool + MLP ----------------
    pool_kernel<<<G_NUM, 256, 0, stream>>>(z, bidx, gbuf);
    mlp_kernel<<<G_NUM, 64, 0, stream>>>(gbuf, mW1, mb1, mW2, mb2, out);
}